// Round 2
// baseline (580.214 us; speedup 1.0000x reference)
//
#include <hip/hip_runtime.h>
#include <hip/hip_bf16.h>

// Problem constants (fixed by reference): N=8192 S=4 Z=64 H=128 K=4 DEG=16
// All float tensors are float32 (in_npz size proves f32, not bf16).
typedef unsigned short u16;

__device__ __forceinline__ float bf2f(u16 v) {
  union { unsigned int u; float f; } x; x.u = ((unsigned int)v) << 16; return x.f;
}
__device__ __forceinline__ u16 f2bf(float f) {
  union { unsigned int u; float f; } x; x.f = f;
  unsigned int r = x.u + 0x7FFFu + ((x.u >> 16) & 1u);  // RNE
  return (u16)(r >> 16);
}
__device__ __forceinline__ float dot4(float4 a, float4 b) {
  return a.x * b.x + a.y * b.y + a.z * b.z + a.w * b.w;
}

// K1: MT[k][z2][z1] = sum_h Ws[k][h][z1] * Wd[k][h][z2]
__global__ __launch_bounds__(256) void k_mt(const float* __restrict__ Ws,
                                            const float* __restrict__ Wd,
                                            float* __restrict__ MT) {
  int t = blockIdx.x * 256 + threadIdx.x;
  int k = t >> 12, z2 = (t >> 6) & 63, z1 = t & 63;
  const float* wsp = Ws + k * 8192 + z1;   // stride 64 over h
  const float* wdp = Wd + k * 8192 + z2;
  float acc = 0.f;
  #pragma unroll 8
  for (int h = 0; h < 128; ++h) acc += wsp[h * 64] * wdp[h * 64];
  MT[k * 4096 + z2 * 64 + z1] = acc;       // coalesced (z1 = lane)
}

// K2a: td[n][s*4+k][z1] = sum_z2 MT[k][z2][z1] * zIG[n][s][z2]; 8 nodes/block
__global__ __launch_bounds__(256) void k_td(const float* __restrict__ zIG,
                                            const float* __restrict__ MT,
                                            float* __restrict__ td) {
  __shared__ float zf[8 * 256];
  int t = threadIdx.x;
  int nb0 = blockIdx.x * 8;
  {
    const float4* zsrc = (const float4*)(zIG + (size_t)nb0 * 256);
    float4* zd = (float4*)zf;
    zd[t] = zsrc[t];
    zd[t + 256] = zsrc[t + 256];
  }
  __syncthreads();
  int s = t >> 6, k = (t >> 4) & 3, z1q = t & 15;  // quad of z1
  const float4* mt4 = (const float4*)MT;
  float4 acc[8];
  #pragma unroll
  for (int g = 0; g < 8; ++g) acc[g] = make_float4(0.f, 0.f, 0.f, 0.f);
  for (int z2 = 0; z2 < 64; ++z2) {
    float4 mv = mt4[k * 1024 + z2 * 16 + z1q];
    #pragma unroll
    for (int g = 0; g < 8; ++g) {
      float zv = zf[g * 256 + s * 64 + z2];          // wave-uniform -> LDS broadcast
      acc[g].x += mv.x * zv; acc[g].y += mv.y * zv;
      acc[g].z += mv.z * zv; acc[g].w += mv.w * zv;
    }
  }
  int sk = s * 4 + k;
  #pragma unroll
  for (int g = 0; g < 8; ++g)
    *(float4*)&td[(size_t)(nb0 + g) * 1024 + sk * 64 + z1q * 4] = acc[g];
}

// K2b: u[n][s][h] = sum_h2 F2_w1[h][h2]*xt[n][s][h2]; v uses cols 128..255.
// 8 nodes/block; u,v stored bf16.
__global__ __launch_bounds__(256) void k_uv(const float* __restrict__ xt,
                                            const float* __restrict__ W1,
                                            u16* __restrict__ u, u16* __restrict__ v) {
  __shared__ float xts[8 * 512];
  int t = threadIdx.x, nb0 = blockIdx.x * 8;
  {
    const float4* xsrc = (const float4*)(xt + (size_t)nb0 * 512);
    float4* xd = (float4*)xts;
    #pragma unroll
    for (int i = 0; i < 4; ++i) xd[t + i * 256] = xsrc[t + i * 256];
  }
  __syncthreads();
  int h = t & 127, half = t >> 7;
  const float4* w1v = (const float4*)W1;             // row = 64 x float4
  float acc[8][4];
  #pragma unroll
  for (int g = 0; g < 8; ++g)
    #pragma unroll
    for (int s = 0; s < 4; ++s) acc[g][s] = 0.f;
  for (int c = 0; c < 32; ++c) {
    float4 w = w1v[h * 64 + half * 32 + c];
    #pragma unroll
    for (int g = 0; g < 8; ++g)
      #pragma unroll
      for (int s = 0; s < 4; ++s) {
        float4 x = *(const float4*)&xts[g * 512 + s * 128 + c * 4];  // uniform -> broadcast
        acc[g][s] += dot4(w, x);
      }
  }
  u16* dstp = half ? v : u;
  #pragma unroll
  for (int g = 0; g < 8; ++g)
    #pragma unroll
    for (int s = 0; s < 4; ++s)
      dstp[(size_t)(nb0 + g) * 512 + s * 128 + h] = f2bf(acc[g][s]);
}

// K3: per dst-node fused: scores -> softmax(alpha out) -> weighted mailbox m ->
//     res = m@W2^T/16 -> hid2 = relu(res_flat@F1w1^T) -> deltax = hid2@F1w2^T
__global__ __launch_bounds__(256) void k_main(
    const float* __restrict__ zIG, const int* __restrict__ src,
    const float* __restrict__ td, const u16* __restrict__ uW, const u16* __restrict__ vW,
    const float* __restrict__ W2f2, const float* __restrict__ W1f1,
    const float* __restrict__ W2f1, float* __restrict__ out) {
  __shared__ int srcIdx[16];
  __shared__ float zs[64 * 68];     // [d*4+s][z] pad 68 (272B rows, 16B-aligned)
  __shared__ float tds[16 * 68];    // [s*4+k][z]
  __shared__ float sc[16 * 17];     // [d][sk]
  __shared__ float al[16 * 17];
  __shared__ float vn[512];
  __shared__ float m_sh[16 * 132];  // [sk][h] pad 132 (528B rows, 16B-aligned)
  __shared__ float res_sh[16 * 132];
  __shared__ float hidp[1024];
  __shared__ float hid2[4 * 132];

  int t = threadIdx.x, n = blockIdx.x;
  if (t < 16) srcIdx[t] = src[n * 16 + t];
  {  // stage td row block (1024 f32) as float4
    int r = t >> 4, cc = t & 15;
    *(float4*)&tds[r * 68 + cc * 4] = ((const float4*)(td + (size_t)n * 1024))[r * 16 + cc];
  }
  if (t < 128) ((float4*)vn)[t] = make_float4(bf2f(vW[(size_t)n * 512 + t * 4]),
                                              bf2f(vW[(size_t)n * 512 + t * 4 + 1]),
                                              bf2f(vW[(size_t)n * 512 + t * 4 + 2]),
                                              bf2f(vW[(size_t)n * 512 + t * 4 + 3]));
  __syncthreads();
  {  // stage gathered z_src rows (f32): row ds=d*4+s, 64 floats each
    int ds = t >> 2, c = t & 3;
    int sn = srcIdx[ds >> 2];
    const float4* zp = (const float4*)(zIG + (size_t)sn * 256 + (ds & 3) * 64) + c * 4;
    float4* zq = (float4*)&zs[ds * 68 + c * 16];
    #pragma unroll
    for (int i = 0; i < 4; ++i) zq[i] = zp[i];
  }
  __syncthreads();
  {  // phase B: scores + leaky_relu
    int d = t >> 4, s = (t >> 2) & 3, k = t & 3;
    int ds = d * 4 + s, sk = s * 4 + k;
    const float4* za = (const float4*)&zs[ds * 68];
    const float4* ta = (const float4*)&tds[sk * 68];
    float acc = 0.f;
    #pragma unroll
    for (int z4 = 0; z4 < 16; ++z4) acc += dot4(za[z4], ta[z4]);
    sc[d * 17 + sk] = acc > 0.f ? acc : 0.01f * acc;
  }
  __syncthreads();
  {  // phase C: softmax over d (redundant 16-way per-thread), write alpha (f32 out)
    int d = t >> 4, sk = t & 15;
    float mx = -3.4e38f;
    #pragma unroll
    for (int dd = 0; dd < 16; ++dd) mx = fmaxf(mx, sc[dd * 17 + sk]);
    float sum = 0.f, eown = 0.f;
    #pragma unroll
    for (int dd = 0; dd < 16; ++dd) {
      float e = expf(sc[dd * 17 + sk] - mx);
      sum += e;
      if (dd == d) eown = e;
    }
    float a = eown / sum;
    al[d * 17 + sk] = a;
    out[4194304u + (unsigned)n * 256 + t] = a;  // alpha [N][16][4][4], t = d*16+sk
  }
  __syncthreads();
  {  // phase D: m[sk][h] = sum_d alpha * relu(u[src]+v[n])
    int h = t & 127, s0 = t >> 7;
    float mac[2][4] = {{0.f,0.f,0.f,0.f},{0.f,0.f,0.f,0.f}};
    for (int d = 0; d < 16; ++d) {
      int sn = srcIdx[d];
      #pragma unroll
      for (int pi = 0; pi < 2; ++pi) {
        int s = s0 + pi * 2;
        float uval = bf2f(uW[(size_t)sn * 512 + s * 128 + h]) + vn[s * 128 + h];
        float hid = uval > 0.f ? uval : 0.f;
        #pragma unroll
        for (int k = 0; k < 4; ++k) mac[pi][k] += al[d * 17 + s * 4 + k] * hid;
      }
    }
    #pragma unroll
    for (int pi = 0; pi < 2; ++pi) {
      int s = s0 + pi * 2;
      #pragma unroll
      for (int k = 0; k < 4; ++k) m_sh[(s * 4 + k) * 132 + h] = mac[pi][k];
    }
  }
  __syncthreads();
  {  // phase E: res = m @ F2_w2^T / 16
    int h = t & 127, g = t >> 7;
    float acc[8] = {0.f,0.f,0.f,0.f,0.f,0.f,0.f,0.f};
    const float4* w2v = (const float4*)W2f2;   // row = 32 x float4
    for (int c = 0; c < 32; ++c) {
      float4 w = w2v[h * 32 + c];
      #pragma unroll
      for (int i = 0; i < 8; ++i) {
        float4 m = *(const float4*)&m_sh[(g * 8 + i) * 132 + c * 4];  // uniform -> broadcast
        acc[i] += dot4(w, m);
      }
    }
    #pragma unroll
    for (int i = 0; i < 8; ++i) res_sh[(g * 8 + i) * 132 + h] = acc[i] * 0.0625f;
  }
  __syncthreads();
  {  // phase F: partial hid2 over j-halves of 512
    int h = t & 127, jh = t >> 7;
    float acc[4] = {0.f,0.f,0.f,0.f};
    const float4* w1v = (const float4*)W1f1;   // row = 128 x float4
    int base = h * 128 + jh * 64;
    for (int c = 0; c < 64; ++c) {
      float4 w = w1v[base + c];
      int jj = jh * 256 + c * 4;
      int kb = jj >> 7, h2 = jj & 127;
      #pragma unroll
      for (int s = 0; s < 4; ++s) {
        float4 r = *(const float4*)&res_sh[(s * 4 + kb) * 132 + h2];
        acc[s] += dot4(w, r);
      }
    }
    #pragma unroll
    for (int s = 0; s < 4; ++s) hidp[jh * 512 + s * 128 + h] = acc[s];
  }
  __syncthreads();
  for (int i = t; i < 512; i += 256) {
    float vv = hidp[i] + hidp[512 + i];
    hid2[(i >> 7) * 132 + (i & 127)] = vv > 0.f ? vv : 0.f;
  }
  __syncthreads();
  {  // phase G: deltax = hid2 @ F1_w2^T
    int h = t & 127, g = t >> 7;
    float acc[2] = {0.f, 0.f};
    const float4* w3v = (const float4*)W2f1;   // row = 32 x float4
    for (int c = 0; c < 32; ++c) {
      float4 w = w3v[h * 32 + c];
      #pragma unroll
      for (int si = 0; si < 2; ++si) {
        float4 hh = *(const float4*)&hid2[(g * 2 + si) * 132 + c * 4];
        acc[si] += dot4(w, hh);
      }
    }
    #pragma unroll
    for (int si = 0; si < 2; ++si)
      out[(unsigned)n * 512 + (g * 2 + si) * 128 + h] = acc[si];
  }
}

extern "C" void kernel_launch(void* const* d_in, const int* in_sizes, int n_in,
                              void* d_out, int out_size, void* d_ws, size_t ws_size,
                              hipStream_t stream) {
  const float* zIG  = (const float*)d_in[0];
  const float* xt   = (const float*)d_in[1];
  const float* Ws   = (const float*)d_in[2];
  const float* Wd   = (const float*)d_in[3];
  const float* F2w1 = (const float*)d_in[4];
  const float* F2w2 = (const float*)d_in[5];
  const float* F1w1 = (const float*)d_in[6];
  const float* F1w2 = (const float*)d_in[7];
  const int* src    = (const int*)d_in[8];
  float* out = (float*)d_out;

  char* ws = (char*)d_ws;
  float* MT = (float*)ws;                             // 16384 f32 = 64 KiB
  float* td = (float*)(ws + 65536);                   // 8.39M f32 = 32 MiB
  u16* u    = (u16*)(ws + 65536 + 33554432);          // 4.19M bf16 = 8 MiB
  u16* v    = u + 4194304;                            // 8 MiB   (total ~48.1 MiB)

  k_mt  <<<64,   256, 0, stream>>>(Ws, Wd, MT);
  k_td  <<<1024, 256, 0, stream>>>(zIG, MT, td);
  k_uv  <<<1024, 256, 0, stream>>>(xt, F2w1, u, v);
  k_main<<<8192, 256, 0, stream>>>(zIG, src, td, u, v, F2w2, F1w1, F1w2, out);
}

// Round 3
// 177.132 us; speedup vs baseline: 3.2756x; 3.2756x over previous
//
#include <hip/hip_runtime.h>
#include <hip/hip_bf16.h>

// Problem constants: N=8192 S=4 Z=64 H=128 K=4 DEG=16. Float tensors are f32.
typedef unsigned short u16;
using ushort8 = __attribute__((ext_vector_type(8))) unsigned short;
using short8  = __attribute__((ext_vector_type(8))) short;
using f32x4   = __attribute__((ext_vector_type(4))) float;

__device__ __forceinline__ float bf2f(u16 v) {
  union { unsigned int u; float f; } x; x.u = ((unsigned int)v) << 16; return x.f;
}
__device__ __forceinline__ u16 f2bf(float f) {
  union { unsigned int u; float f; } x; x.f = f;
  unsigned int r = x.u + 0x7FFFu + ((x.u >> 16) & 1u);  // RNE
  return (u16)(r >> 16);
}
__device__ __forceinline__ float dot4(float4 a, float4 b) {
  return a.x * b.x + a.y * b.y + a.z * b.z + a.w * b.w;
}

// K1: MT[k][z2][z1] = sum_h Ws[k][h][z1] * Wd[k][h][z2]
__global__ __launch_bounds__(256) void k_mt(const float* __restrict__ Ws,
                                            const float* __restrict__ Wd,
                                            float* __restrict__ MT) {
  int t = blockIdx.x * 256 + threadIdx.x;
  int k = t >> 12, z2 = (t >> 6) & 63, z1 = t & 63;
  const float* wsp = Ws + k * 8192 + z1;
  const float* wdp = Wd + k * 8192 + z2;
  float acc = 0.f;
  #pragma unroll 8
  for (int h = 0; h < 128; ++h) acc += wsp[h * 64] * wdp[h * 64];
  MT[k * 4096 + z2 * 64 + z1] = acc;
}

// K2a: td[n][s*4+k][z1] = sum_z2 MT[k][z2][z1] * zIG[n][s][z2]; 8 nodes/block
__global__ __launch_bounds__(256) void k_td(const float* __restrict__ zIG,
                                            const float* __restrict__ MT,
                                            float* __restrict__ td) {
  __shared__ float zf[8 * 256];
  int t = threadIdx.x;
  int nb0 = blockIdx.x * 8;
  {
    const float4* zsrc = (const float4*)(zIG + (size_t)nb0 * 256);
    float4* zd = (float4*)zf;
    zd[t] = zsrc[t];
    zd[t + 256] = zsrc[t + 256];
  }
  __syncthreads();
  int s = t >> 6, k = (t >> 4) & 3, z1q = t & 15;
  const float4* mt4 = (const float4*)MT;
  float4 acc[8];
  #pragma unroll
  for (int g = 0; g < 8; ++g) acc[g] = make_float4(0.f, 0.f, 0.f, 0.f);
  for (int z2 = 0; z2 < 64; ++z2) {
    float4 mv = mt4[k * 1024 + z2 * 16 + z1q];
    #pragma unroll
    for (int g = 0; g < 8; ++g) {
      float zv = zf[g * 256 + s * 64 + z2];
      acc[g].x += mv.x * zv; acc[g].y += mv.y * zv;
      acc[g].z += mv.z * zv; acc[g].w += mv.w * zv;
    }
  }
  int sk = s * 4 + k;
  #pragma unroll
  for (int g = 0; g < 8; ++g)
    *(float4*)&td[(size_t)(nb0 + g) * 1024 + sk * 64 + z1q * 4] = acc[g];
}

// K2b: u[n][s][h] = F2_w1[:, :128] @ xt ; v = F2_w1[:, 128:] @ xt. 8 nodes/block, bf16 out.
__global__ __launch_bounds__(256) void k_uv(const float* __restrict__ xt,
                                            const float* __restrict__ W1,
                                            u16* __restrict__ u, u16* __restrict__ v) {
  __shared__ float xts[8 * 512];
  int t = threadIdx.x, nb0 = blockIdx.x * 8;
  {
    const float4* xsrc = (const float4*)(xt + (size_t)nb0 * 512);
    float4* xd = (float4*)xts;
    #pragma unroll
    for (int i = 0; i < 4; ++i) xd[t + i * 256] = xsrc[t + i * 256];
  }
  __syncthreads();
  int h = t & 127, half = t >> 7;
  const float4* w1v = (const float4*)W1;
  float acc[8][4];
  #pragma unroll
  for (int g = 0; g < 8; ++g)
    #pragma unroll
    for (int s = 0; s < 4; ++s) acc[g][s] = 0.f;
  for (int c = 0; c < 32; ++c) {
    float4 w = w1v[h * 64 + half * 32 + c];
    #pragma unroll
    for (int g = 0; g < 8; ++g)
      #pragma unroll
      for (int s = 0; s < 4; ++s) {
        float4 x = *(const float4*)&xts[g * 512 + s * 128 + c * 4];
        acc[g][s] += dot4(w, x);
      }
  }
  u16* dstp = half ? v : u;
  #pragma unroll
  for (int g = 0; g < 8; ++g)
    #pragma unroll
    for (int s = 0; s < 4; ++s)
      dstp[(size_t)(nb0 + g) * 512 + s * 128 + h] = f2bf(acc[g][s]);
}

// Cast the three epilogue weight matrices to bf16 (16384 + 65536 + 16384 elems).
__global__ __launch_bounds__(256) void k_castw(const float* __restrict__ a,
                                               const float* __restrict__ b,
                                               const float* __restrict__ c,
                                               u16* __restrict__ wa, u16* __restrict__ wb,
                                               u16* __restrict__ wc) {
  int i = blockIdx.x * 256 + threadIdx.x;
  if (i < 16384) wa[i] = f2bf(a[i]);
  else if (i < 81920) wb[i - 16384] = f2bf(b[i - 16384]);
  else wc[i - 81920] = f2bf(c[i - 81920]);
}

// K3: per dst-node: gather z_src, scores+leaky_relu, softmax (alpha out, f32 exact),
//     mailbox m[sk][h] = sum_d alpha*relu(u[src]+v[n])  -> m bf16 to workspace.
__global__ __launch_bounds__(256) void k_score(
    const float* __restrict__ zIG, const int* __restrict__ src,
    const float* __restrict__ td, const u16* __restrict__ uW, const u16* __restrict__ vW,
    float* __restrict__ out, u16* __restrict__ m_ws) {
  __shared__ int srcIdx[16];
  __shared__ float zs[64 * 68];
  __shared__ float tds[16 * 68];
  __shared__ float sc[16 * 17];
  __shared__ float al[16 * 17];
  __shared__ float vn[512];

  int t = threadIdx.x, n = blockIdx.x;
  if (t < 16) srcIdx[t] = src[n * 16 + t];
  {
    int r = t >> 4, cc = t & 15;
    *(float4*)&tds[r * 68 + cc * 4] = ((const float4*)(td + (size_t)n * 1024))[r * 16 + cc];
  }
  if (t < 128) ((float4*)vn)[t] = make_float4(bf2f(vW[(size_t)n * 512 + t * 4]),
                                              bf2f(vW[(size_t)n * 512 + t * 4 + 1]),
                                              bf2f(vW[(size_t)n * 512 + t * 4 + 2]),
                                              bf2f(vW[(size_t)n * 512 + t * 4 + 3]));
  __syncthreads();
  {  // stage gathered z_src rows (f32): row ds=d*4+s, 64 floats
    int ds = t >> 2, c = t & 3;
    int sn = srcIdx[ds >> 2];
    const float4* zp = (const float4*)(zIG + (size_t)sn * 256 + (ds & 3) * 64) + c * 4;
    float4* zq = (float4*)&zs[ds * 68 + c * 16];
    #pragma unroll
    for (int i = 0; i < 4; ++i) zq[i] = zp[i];
  }
  __syncthreads();
  {  // scores + leaky_relu
    int d = t >> 4, s = (t >> 2) & 3, k = t & 3;
    int ds = d * 4 + s, sk = s * 4 + k;
    const float4* za = (const float4*)&zs[ds * 68];
    const float4* ta = (const float4*)&tds[sk * 68];
    float acc = 0.f;
    #pragma unroll
    for (int z4 = 0; z4 < 16; ++z4) acc += dot4(za[z4], ta[z4]);
    sc[d * 17 + sk] = acc > 0.f ? acc : 0.01f * acc;
  }
  __syncthreads();
  {  // softmax over d; alpha out (f32)
    int d = t >> 4, sk = t & 15;
    float mx = -3.4e38f;
    #pragma unroll
    for (int dd = 0; dd < 16; ++dd) mx = fmaxf(mx, sc[dd * 17 + sk]);
    float sum = 0.f, eown = 0.f;
    #pragma unroll
    for (int dd = 0; dd < 16; ++dd) {
      float e = expf(sc[dd * 17 + sk] - mx);
      sum += e;
      if (dd == d) eown = e;
    }
    float a = eown / sum;
    al[d * 17 + sk] = a;
    out[4194304u + (unsigned)n * 256 + t] = a;  // alpha [N][16][4][4]
  }
  __syncthreads();
  {  // mailbox: m[sk][h] = sum_d alpha * relu(u[src]+v[n]); bf16 to ws
    int h = t & 127, s0 = t >> 7;
    float mac[2][4] = {{0.f,0.f,0.f,0.f},{0.f,0.f,0.f,0.f}};
    for (int d = 0; d < 16; ++d) {
      int sn = srcIdx[d];
      #pragma unroll
      for (int pi = 0; pi < 2; ++pi) {
        int s = s0 + pi * 2;
        float uval = bf2f(uW[(size_t)sn * 512 + s * 128 + h]) + vn[s * 128 + h];
        float hid = uval > 0.f ? uval : 0.f;
        #pragma unroll
        for (int k = 0; k < 4; ++k) mac[pi][k] += al[d * 17 + s * 4 + k] * hid;
      }
    }
    #pragma unroll
    for (int pi = 0; pi < 2; ++pi) {
      int s = s0 + pi * 2;
      #pragma unroll
      for (int k = 0; k < 4; ++k)
        m_ws[(size_t)n * 2048 + (s * 4 + k) * 128 + h] = f2bf(mac[pi][k]);
    }
  }
}

// Batched GEMM: C[M x 128] = act( A[M x KDIM] @ W[128 x KDIM]^T * scale ).
// Block = 128 rows (4 waves x 32 rows). W chunk (128 x 64 bf16) staged in LDS,
// row pad 72 bf16 -> frag reads perfectly bank-balanced (8 words/bank).
// A-frag direct global->reg. In-place A==C is safe: each wave stores only the
// rows it alone reads, after all its loads.
template<int KDIM, bool RELU, bool OUTF32>
__global__ __launch_bounds__(256) void k_gemm(const u16* A, const u16* __restrict__ W,
                                              void* Cout, float scale) {
  __shared__ u16 Wl[128 * 72];
  int t = threadIdx.x;
  int lane = t & 63, w = t >> 6;
  size_t rowbase = (size_t)blockIdx.x * 128 + w * 32;
  int l15 = lane & 15, kc = lane >> 4;
  f32x4 acc[2][8];
  #pragma unroll
  for (int mt = 0; mt < 2; ++mt)
    #pragma unroll
    for (int nt = 0; nt < 8; ++nt) acc[mt][nt] = (f32x4){0.f, 0.f, 0.f, 0.f};

  for (int c = 0; c < KDIM / 64; ++c) {
    __syncthreads();
    {  // stage W chunk: 128 rows x 64 bf16
      int n = t >> 1, off = (t & 1) * 32;
      const ushort8* g = (const ushort8*)(W + (size_t)n * KDIM + c * 64 + off);
      ushort8* d = (ushort8*)(Wl + n * 72 + off);
      d[0] = g[0]; d[1] = g[1]; d[2] = g[2]; d[3] = g[3];
    }
    __syncthreads();
    #pragma unroll
    for (int ks = 0; ks < 2; ++ks) {
      short8 af[2];
      #pragma unroll
      for (int mt = 0; mt < 2; ++mt)
        af[mt] = *(const short8*)(A + (rowbase + mt * 16 + l15) * KDIM + c * 64 + ks * 32 + kc * 8);
      #pragma unroll
      for (int nt = 0; nt < 8; ++nt) {
        short8 bf = *(const short8*)&Wl[(nt * 16 + l15) * 72 + ks * 32 + kc * 8];
        #pragma unroll
        for (int mt = 0; mt < 2; ++mt)
          acc[mt][nt] = __builtin_amdgcn_mfma_f32_16x16x32_bf16(af[mt], bf, acc[mt][nt], 0, 0, 0);
      }
    }
  }
  #pragma unroll
  for (int mt = 0; mt < 2; ++mt)
    #pragma unroll
    for (int nt = 0; nt < 8; ++nt)
      #pragma unroll
      for (int j = 0; j < 4; ++j) {
        float vv = acc[mt][nt][j] * scale;
        if (RELU) vv = fmaxf(vv, 0.f);
        size_t idx = (rowbase + mt * 16 + kc * 4 + j) * 128 + nt * 16 + l15;
        if (OUTF32) ((float*)Cout)[idx] = vv;
        else        ((u16*)Cout)[idx] = f2bf(vv);
      }
}

extern "C" void kernel_launch(void* const* d_in, const int* in_sizes, int n_in,
                              void* d_out, int out_size, void* d_ws, size_t ws_size,
                              hipStream_t stream) {
  const float* zIG  = (const float*)d_in[0];
  const float* xt   = (const float*)d_in[1];
  const float* Ws   = (const float*)d_in[2];
  const float* Wd   = (const float*)d_in[3];
  const float* F2w1 = (const float*)d_in[4];
  const float* F2w2 = (const float*)d_in[5];
  const float* F1w1 = (const float*)d_in[6];
  const float* F1w2 = (const float*)d_in[7];
  const int* src    = (const int*)d_in[8];
  float* out = (float*)d_out;

  char* ws = (char*)d_ws;
  float* MT = (float*)ws;                          // 64 KiB
  float* td = (float*)(ws + 65536);                // 32 MiB (f32 [N][16][64])
  u16* u    = (u16*)(ws + 65536 + 33554432);       // 8 MiB
  u16* v    = u + 4194304;                         // 8 MiB
  u16* wbE  = v + 4194304;                         // 32 KiB  (W2f2 bf16)
  u16* wbF  = wbE + 16384;                         // 128 KiB (F1w1 bf16)
  u16* wbG  = wbF + 65536;                         // 32 KiB  (F1w2 bf16)
  u16* mres = wbG + 16384;                         // 32 MiB  (m, then res in-place)
  u16* hid  = (u16*)td;                            // reuse td region (dead after k_score)

  k_mt   <<<64,   256, 0, stream>>>(Ws, Wd, MT);
  k_td   <<<1024, 256, 0, stream>>>(zIG, MT, td);
  k_uv   <<<1024, 256, 0, stream>>>(xt, F2w1, u, v);
  k_castw<<<384,  256, 0, stream>>>(F2w2, F1w1, F1w2, wbE, wbF, wbG);
  k_score<<<8192, 256, 0, stream>>>(zIG, src, td, u, v, out, mres);
  // E: res = (m @ W2f2^T)/16, in-place over m.  M=131072
  k_gemm<128, false, false><<<1024, 256, 0, stream>>>(mres, wbE, mres, 0.0625f);
  // F: hid = relu(res @ F1w1^T).  M=32768 rows of 512
  k_gemm<512, true, false><<<256, 256, 0, stream>>>(mres, wbF, hid, 1.0f);
  // G: deltax = hid @ F1w2^T -> f32 out.  M=32768
  k_gemm<128, false, true><<<256, 256, 0, stream>>>(hid, wbG, out, 1.0f);
}

// Round 4
// 147.641 us; speedup vs baseline: 3.9299x; 1.1998x over previous
//
#include <hip/hip_runtime.h>
#include <hip/hip_bf16.h>

// Problem constants: N=8192 S=4 Z=64 H=128 K=4 DEG=16. Float tensors are f32.
typedef unsigned short u16;
using ushort8 = __attribute__((ext_vector_type(8))) unsigned short;
using short8  = __attribute__((ext_vector_type(8))) short;
using f32x4   = __attribute__((ext_vector_type(4))) float;

__device__ __forceinline__ float bf2f(u16 v) {
  union { unsigned int u; float f; } x; x.u = ((unsigned int)v) << 16; return x.f;
}
__device__ __forceinline__ u16 f2bf(float f) {
  union { unsigned int u; float f; } x; x.f = f;
  unsigned int r = x.u + 0x7FFFu + ((x.u >> 16) & 1u);  // RNE
  return (u16)(r >> 16);
}
__device__ __forceinline__ float dot4(float4 a, float4 b) {
  return a.x * b.x + a.y * b.y + a.z * b.z + a.w * b.w;
}

// K1: MT[k][z2][z1] = sum_h Ws[k][h][z1] * Wd[k][h][z2]
__global__ __launch_bounds__(256) void k_mt(const float* __restrict__ Ws,
                                            const float* __restrict__ Wd,
                                            float* __restrict__ MT) {
  int t = blockIdx.x * 256 + threadIdx.x;
  int k = t >> 12, z2 = (t >> 6) & 63, z1 = t & 63;
  const float* wsp = Ws + k * 8192 + z1;
  const float* wdp = Wd + k * 8192 + z2;
  float acc = 0.f;
  #pragma unroll 8
  for (int h = 0; h < 128; ++h) acc += wsp[h * 64] * wdp[h * 64];
  MT[k * 4096 + z2 * 64 + z1] = acc;
}

// K2a: td[n][s*4+k][z1] = sum_z2 MT[k][z2][z1] * zIG[n][s][z2]; 8 nodes/block
__global__ __launch_bounds__(256) void k_td(const float* __restrict__ zIG,
                                            const float* __restrict__ MT,
                                            float* __restrict__ td) {
  __shared__ float zf[8 * 256];
  int t = threadIdx.x;
  int nb0 = blockIdx.x * 8;
  {
    const float4* zsrc = (const float4*)(zIG + (size_t)nb0 * 256);
    float4* zd = (float4*)zf;
    zd[t] = zsrc[t];
    zd[t + 256] = zsrc[t + 256];
  }
  __syncthreads();
  int s = t >> 6, k = (t >> 4) & 3, z1q = t & 15;
  const float4* mt4 = (const float4*)MT;
  float4 acc[8];
  #pragma unroll
  for (int g = 0; g < 8; ++g) acc[g] = make_float4(0.f, 0.f, 0.f, 0.f);
  for (int z2 = 0; z2 < 64; ++z2) {
    float4 mv = mt4[k * 1024 + z2 * 16 + z1q];
    #pragma unroll
    for (int g = 0; g < 8; ++g) {
      float zv = zf[g * 256 + s * 64 + z2];
      acc[g].x += mv.x * zv; acc[g].y += mv.y * zv;
      acc[g].z += mv.z * zv; acc[g].w += mv.w * zv;
    }
  }
  int sk = s * 4 + k;
  #pragma unroll
  for (int g = 0; g < 8; ++g)
    *(float4*)&td[(size_t)(nb0 + g) * 1024 + sk * 64 + z1q * 4] = acc[g];
}

// Cast xt (f32, 4194304 elems) to bf16. Grid-stride float4.
__global__ __launch_bounds__(256) void k_castxt(const float* __restrict__ x,
                                                u16* __restrict__ xb) {
  int i = blockIdx.x * 256 + threadIdx.x;   // 1048576 threads, 4 elems each
  float4 v = ((const float4*)x)[i];
  u16 o[4] = {f2bf(v.x), f2bf(v.y), f2bf(v.z), f2bf(v.w)};
  *(ulong1*)&xb[i * 4] = *(ulong1*)o;
}

// K3: per dst-node: gather z_src, scores+leaky_relu, softmax (alpha out, f32 exact),
//     mailbox m[sk][h] = sum_d alpha*relu(u[src]+v[n])  -> m bf16 to workspace.
__global__ __launch_bounds__(256) void k_score(
    const float* __restrict__ zIG, const int* __restrict__ src,
    const float* __restrict__ td, const u16* __restrict__ uW, const u16* __restrict__ vW,
    float* __restrict__ out, u16* __restrict__ m_ws) {
  __shared__ int srcIdx[16];
  __shared__ float zs[64 * 68];
  __shared__ float tds[16 * 68];
  __shared__ float sc[16 * 17];
  __shared__ float al[16 * 17];
  __shared__ float vn[512];

  int t = threadIdx.x, n = blockIdx.x;
  if (t < 16) srcIdx[t] = src[n * 16 + t];
  {
    int r = t >> 4, cc = t & 15;
    *(float4*)&tds[r * 68 + cc * 4] = ((const float4*)(td + (size_t)n * 1024))[r * 16 + cc];
  }
  if (t < 128) ((float4*)vn)[t] = make_float4(bf2f(vW[(size_t)n * 512 + t * 4]),
                                              bf2f(vW[(size_t)n * 512 + t * 4 + 1]),
                                              bf2f(vW[(size_t)n * 512 + t * 4 + 2]),
                                              bf2f(vW[(size_t)n * 512 + t * 4 + 3]));
  __syncthreads();
  {  // stage gathered z_src rows (f32): row ds=d*4+s, 64 floats
    int ds = t >> 2, c = t & 3;
    int sn = srcIdx[ds >> 2];
    const float4* zp = (const float4*)(zIG + (size_t)sn * 256 + (ds & 3) * 64) + c * 4;
    float4* zq = (float4*)&zs[ds * 68 + c * 16];
    #pragma unroll
    for (int i = 0; i < 4; ++i) zq[i] = zp[i];
  }
  __syncthreads();
  {  // scores + leaky_relu
    int d = t >> 4, s = (t >> 2) & 3, k = t & 3;
    int ds = d * 4 + s, sk = s * 4 + k;
    const float4* za = (const float4*)&zs[ds * 68];
    const float4* ta = (const float4*)&tds[sk * 68];
    float acc = 0.f;
    #pragma unroll
    for (int z4 = 0; z4 < 16; ++z4) acc += dot4(za[z4], ta[z4]);
    sc[d * 17 + sk] = acc > 0.f ? acc : 0.01f * acc;
  }
  __syncthreads();
  {  // softmax over d; alpha out (f32)
    int d = t >> 4, sk = t & 15;
    float mx = -3.4e38f;
    #pragma unroll
    for (int dd = 0; dd < 16; ++dd) mx = fmaxf(mx, sc[dd * 17 + sk]);
    float sum = 0.f, eown = 0.f;
    #pragma unroll
    for (int dd = 0; dd < 16; ++dd) {
      float e = expf(sc[dd * 17 + sk] - mx);
      sum += e;
      if (dd == d) eown = e;
    }
    float a = eown / sum;
    al[d * 17 + sk] = a;
    out[4194304u + (unsigned)n * 256 + t] = a;  // alpha [N][16][4][4]
  }
  __syncthreads();
  {  // mailbox: m[sk][h] = sum_d alpha * relu(u[src]+v[n]); bf16 to ws
    int h = t & 127, s0 = t >> 7;
    float mac[2][4] = {{0.f,0.f,0.f,0.f},{0.f,0.f,0.f,0.f}};
    for (int d = 0; d < 16; ++d) {
      int sn = srcIdx[d];
      #pragma unroll
      for (int pi = 0; pi < 2; ++pi) {
        int s = s0 + pi * 2;
        float uval = bf2f(uW[(size_t)sn * 512 + s * 128 + h]) + vn[s * 128 + h];
        float hid = uval > 0.f ? uval : 0.f;
        #pragma unroll
        for (int k = 0; k < 4; ++k) mac[pi][k] += al[d * 17 + s * 4 + k] * hid;
      }
    }
    #pragma unroll
    for (int pi = 0; pi < 2; ++pi) {
      int s = s0 + pi * 2;
      #pragma unroll
      for (int k = 0; k < 4; ++k)
        m_ws[(size_t)n * 2048 + (s * 4 + k) * 128 + h] = f2bf(mac[pi][k]);
    }
  }
}

// Batched GEMM: C[M x 128] = act( A[M x KDIM](bf16) @ W[128 x KDIM](f32,row-stride ws)^T * scale ).
// Block = 128 rows (4 waves x 32 rows). W chunk (128 x 64) converted f32->bf16 while
// staging into LDS, row pad 72 bf16 -> frag reads bank-balanced (8 lanes / 4-bank window).
// A-frag direct global->reg. In-place A==C safe: each wave reads only the rows it writes.
template<int KDIM, bool RELU, bool OUTF32>
__global__ __launch_bounds__(256) void k_gemm(const u16* A, const float* __restrict__ W,
                                              int wstride, void* Cout, float scale) {
  __shared__ u16 Wl[128 * 72];
  int t = threadIdx.x;
  int lane = t & 63, w = t >> 6;
  size_t rowbase = (size_t)blockIdx.x * 128 + w * 32;
  int l15 = lane & 15, kc = lane >> 4;
  f32x4 acc[2][8];
  #pragma unroll
  for (int mt = 0; mt < 2; ++mt)
    #pragma unroll
    for (int nt = 0; nt < 8; ++nt) acc[mt][nt] = (f32x4){0.f, 0.f, 0.f, 0.f};

  for (int c = 0; c < KDIM / 64; ++c) {
    __syncthreads();
    {  // stage W chunk: 128 rows x 64 cols, f32 -> bf16
      int row = t >> 1, half = t & 1;
      const float4* g = (const float4*)(W + (size_t)row * wstride + c * 64 + half * 32);
      ushort8* d = (ushort8*)(Wl + row * 72 + half * 32);
      #pragma unroll
      for (int i = 0; i < 4; ++i) {
        float4 a = g[2 * i], b = g[2 * i + 1];
        ushort8 o;
        o[0] = f2bf(a.x); o[1] = f2bf(a.y); o[2] = f2bf(a.z); o[3] = f2bf(a.w);
        o[4] = f2bf(b.x); o[5] = f2bf(b.y); o[6] = f2bf(b.z); o[7] = f2bf(b.w);
        d[i] = o;
      }
    }
    __syncthreads();
    #pragma unroll
    for (int ks = 0; ks < 2; ++ks) {
      short8 af[2];
      #pragma unroll
      for (int mt = 0; mt < 2; ++mt)
        af[mt] = *(const short8*)(A + (rowbase + mt * 16 + l15) * KDIM + c * 64 + ks * 32 + kc * 8);
      #pragma unroll
      for (int nt = 0; nt < 8; ++nt) {
        short8 bf = *(const short8*)&Wl[(nt * 16 + l15) * 72 + ks * 32 + kc * 8];
        #pragma unroll
        for (int mt = 0; mt < 2; ++mt)
          acc[mt][nt] = __builtin_amdgcn_mfma_f32_16x16x32_bf16(af[mt], bf, acc[mt][nt], 0, 0, 0);
      }
    }
  }
  #pragma unroll
  for (int mt = 0; mt < 2; ++mt)
    #pragma unroll
    for (int nt = 0; nt < 8; ++nt)
      #pragma unroll
      for (int j = 0; j < 4; ++j) {
        float vv = acc[mt][nt][j] * scale;
        if (RELU) vv = fmaxf(vv, 0.f);
        size_t idx = (rowbase + mt * 16 + kc * 4 + j) * 128 + nt * 16 + l15;
        if (OUTF32) ((float*)Cout)[idx] = vv;
        else        ((u16*)Cout)[idx] = f2bf(vv);
      }
}

extern "C" void kernel_launch(void* const* d_in, const int* in_sizes, int n_in,
                              void* d_out, int out_size, void* d_ws, size_t ws_size,
                              hipStream_t stream) {
  const float* zIG  = (const float*)d_in[0];
  const float* xt   = (const float*)d_in[1];
  const float* Ws   = (const float*)d_in[2];
  const float* Wd   = (const float*)d_in[3];
  const float* F2w1 = (const float*)d_in[4];
  const float* F2w2 = (const float*)d_in[5];
  const float* F1w1 = (const float*)d_in[6];
  const float* F1w2 = (const float*)d_in[7];
  const int* src    = (const int*)d_in[8];
  float* out = (float*)d_out;

  char* ws = (char*)d_ws;
  float* MT = (float*)ws;                          // 64 KiB
  float* td = (float*)(ws + 65536);                // 32 MiB (f32 [N][16][64])
  u16* u    = (u16*)(ws + 65536 + 33554432);       // 8 MiB
  u16* v    = u + 4194304;                         // 8 MiB
  u16* xtb  = v + 4194304;                         // 8 MiB (xt bf16)
  u16* mres = xtb + 4194304;                       // 32 MiB (m, then res in-place)
  u16* hid  = (u16*)td;                            // reuse td region (dead after k_score)

  k_mt    <<<64,   256, 0, stream>>>(Ws, Wd, MT);
  k_td    <<<1024, 256, 0, stream>>>(zIG, MT, td);
  k_castxt<<<4096, 256, 0, stream>>>(xt, xtb);
  // u = xtb @ F2w1[:, :128]^T ; v = xtb @ F2w1[:, 128:]^T   (M=32768)
  k_gemm<128, false, false><<<256, 256, 0, stream>>>(xtb, F2w1,       256, u, 1.0f);
  k_gemm<128, false, false><<<256, 256, 0, stream>>>(xtb, F2w1 + 128, 256, v, 1.0f);
  k_score <<<8192, 256, 0, stream>>>(zIG, src, td, u, v, out, mres);
  // E: res = (m @ F2w2^T)/16, in-place over m.  M=131072
  k_gemm<128, false, false><<<1024, 256, 0, stream>>>(mres, F2w2, 128, mres, 0.0625f);
  // F: hid = relu(res @ F1w1^T).  M=32768 rows of 512
  k_gemm<512, true, false><<<256, 256, 0, stream>>>(mres, F1w1, 512, hid, 1.0f);
  // G: deltax = hid @ F1w2^T -> f32 out.  M=32768
  k_gemm<128, false, true><<<256, 256, 0, stream>>>(hid, F1w2, 128, out, 1.0f);
}

// Round 5
// 123.282 us; speedup vs baseline: 4.7064x; 1.1976x over previous
//
#include <hip/hip_runtime.h>
#include <hip/hip_bf16.h>

// Problem constants: N=8192 S=4 Z=64 H=128 K=4 DEG=16. Float tensors are f32.
typedef unsigned short u16;
using ushort8 = __attribute__((ext_vector_type(8))) unsigned short;
using short8  = __attribute__((ext_vector_type(8))) short;
using f32x4   = __attribute__((ext_vector_type(4))) float;

__device__ __forceinline__ float bf2f(u16 v) {
  union { unsigned int u; float f; } x; x.u = ((unsigned int)v) << 16; return x.f;
}
__device__ __forceinline__ u16 f2bf(float f) {
  union { unsigned int u; float f; } x; x.f = f;
  unsigned int r = x.u + 0x7FFFu + ((x.u >> 16) & 1u);  // RNE
  return (u16)(r >> 16);
}
__device__ __forceinline__ float dot4(float4 a, float4 b) {
  return a.x * b.x + a.y * b.y + a.z * b.z + a.w * b.w;
}
// Stage a 128x64 f32 chunk (row stride `stride`, col offset c*64) into LDS bf16 [128][72].
__device__ __forceinline__ void stage_w(const float* g, int stride, int c, u16* Wl, int t) {
  int row = t >> 1, half = t & 1;
  const float4* gp = (const float4*)(g + (size_t)row * stride + c * 64 + half * 32);
  ushort8* d = (ushort8*)(Wl + row * 72 + half * 32);
  #pragma unroll
  for (int i = 0; i < 4; ++i) {
    float4 a = gp[2 * i], b = gp[2 * i + 1];
    ushort8 o;
    o[0] = f2bf(a.x); o[1] = f2bf(a.y); o[2] = f2bf(a.z); o[3] = f2bf(a.w);
    o[4] = f2bf(b.x); o[5] = f2bf(b.y); o[6] = f2bf(b.z); o[7] = f2bf(b.w);
    d[i] = o;
  }
}

// K1: MT[k][z2][z1] = sum_h Ws[k][h][z1] * Wd[k][h][z2]
__global__ __launch_bounds__(256) void k_mt(const float* __restrict__ Ws,
                                            const float* __restrict__ Wd,
                                            float* __restrict__ MT) {
  int t = blockIdx.x * 256 + threadIdx.x;
  int k = t >> 12, z2 = (t >> 6) & 63, z1 = t & 63;
  const float* wsp = Ws + k * 8192 + z1;
  const float* wdp = Wd + k * 8192 + z2;
  float acc = 0.f;
  #pragma unroll 8
  for (int h = 0; h < 128; ++h) acc += wsp[h * 64] * wdp[h * 64];
  MT[k * 4096 + z2 * 64 + z1] = acc;
}

// K2a: td[n][s*4+k][z1] = sum_z2 MT[k][z2][z1] * zIG[n][s][z2]; 8 nodes/block
__global__ __launch_bounds__(256) void k_td(const float* __restrict__ zIG,
                                            const float* __restrict__ MT,
                                            float* __restrict__ td) {
  __shared__ float zf[8 * 256];
  int t = threadIdx.x;
  int nb0 = blockIdx.x * 8;
  {
    const float4* zsrc = (const float4*)(zIG + (size_t)nb0 * 256);
    float4* zd = (float4*)zf;
    zd[t] = zsrc[t];
    zd[t + 256] = zsrc[t + 256];
  }
  __syncthreads();
  int s = t >> 6, k = (t >> 4) & 3, z1q = t & 15;
  const float4* mt4 = (const float4*)MT;
  float4 acc[8];
  #pragma unroll
  for (int g = 0; g < 8; ++g) acc[g] = make_float4(0.f, 0.f, 0.f, 0.f);
  for (int z2 = 0; z2 < 64; ++z2) {
    float4 mv = mt4[k * 1024 + z2 * 16 + z1q];
    #pragma unroll
    for (int g = 0; g < 8; ++g) {
      float zv = zf[g * 256 + s * 64 + z2];
      acc[g].x += mv.x * zv; acc[g].y += mv.y * zv;
      acc[g].z += mv.z * zv; acc[g].w += mv.w * zv;
    }
  }
  int sk = s * 4 + k;
  #pragma unroll
  for (int g = 0; g < 8; ++g)
    *(float4*)&td[(size_t)(nb0 + g) * 1024 + sk * 64 + z1q * 4] = acc[g];
}

// Composite epilogue weight: WW2[ho][k*128+hi] = (1/16) sum_j F1w1[ho][k*128+j]*F2w2[j][hi]
__global__ __launch_bounds__(256) void k_ww(const float* __restrict__ F1w1,
                                            const float* __restrict__ F2w2,
                                            float* __restrict__ WW2) {
  int id = blockIdx.x * 256 + threadIdx.x;   // 65536 = 128 ho x 4 k x 128 hi
  int ho = id >> 9, kk = (id >> 7) & 3, hi = id & 127;
  const float* wa = F1w1 + ho * 512 + kk * 128;  // wave-uniform -> scalar loads
  const float* wb = F2w2 + hi;                    // coalesced over hi
  float acc = 0.f;
  #pragma unroll 8
  for (int j = 0; j < 128; ++j) acc += wa[j] * wb[j * 128];
  WW2[ho * 512 + kk * 128 + hi] = acc * 0.0625f;
}

// K2b: u = xt @ F2w1[:, :128]^T, v = xt @ F2w1[:, 128:]^T in ONE pass (shared A-frags).
// A read f32, converted in-register. M=32768 rows; block = 128 rows, 4 waves.
__global__ __launch_bounds__(256) void k_uv(const float* __restrict__ xt,
                                            const float* __restrict__ W1,   // [128][256]
                                            u16* __restrict__ u, u16* __restrict__ v) {
  __shared__ u16 Wlu[128 * 72];
  __shared__ u16 Wlv[128 * 72];
  int t = threadIdx.x, lane = t & 63, w = t >> 6;
  size_t rowbase = (size_t)blockIdx.x * 128 + w * 32;
  int l15 = lane & 15, kc = lane >> 4;
  f32x4 au[2][8], av[2][8];
  #pragma unroll
  for (int mt = 0; mt < 2; ++mt)
    #pragma unroll
    for (int nt = 0; nt < 8; ++nt) {
      au[mt][nt] = (f32x4){0.f, 0.f, 0.f, 0.f};
      av[mt][nt] = (f32x4){0.f, 0.f, 0.f, 0.f};
    }
  for (int c = 0; c < 2; ++c) {
    __syncthreads();
    stage_w(W1,       256, c, Wlu, t);
    stage_w(W1 + 128, 256, c, Wlv, t);
    __syncthreads();
    #pragma unroll
    for (int ks = 0; ks < 2; ++ks) {
      short8 af[2];
      #pragma unroll
      for (int mt = 0; mt < 2; ++mt) {
        const float* ap = xt + (rowbase + mt * 16 + l15) * 128 + c * 64 + ks * 32 + kc * 8;
        float4 a0 = *(const float4*)ap, a1 = *(const float4*)(ap + 4);
        u16 tmp[8] = {f2bf(a0.x), f2bf(a0.y), f2bf(a0.z), f2bf(a0.w),
                      f2bf(a1.x), f2bf(a1.y), f2bf(a1.z), f2bf(a1.w)};
        af[mt] = *(short8*)tmp;
      }
      #pragma unroll
      for (int nt = 0; nt < 8; ++nt) {
        short8 bu = *(const short8*)&Wlu[(nt * 16 + l15) * 72 + ks * 32 + kc * 8];
        short8 bv = *(const short8*)&Wlv[(nt * 16 + l15) * 72 + ks * 32 + kc * 8];
        #pragma unroll
        for (int mt = 0; mt < 2; ++mt) {
          au[mt][nt] = __builtin_amdgcn_mfma_f32_16x16x32_bf16(af[mt], bu, au[mt][nt], 0, 0, 0);
          av[mt][nt] = __builtin_amdgcn_mfma_f32_16x16x32_bf16(af[mt], bv, av[mt][nt], 0, 0, 0);
        }
      }
    }
  }
  #pragma unroll
  for (int mt = 0; mt < 2; ++mt)
    #pragma unroll
    for (int nt = 0; nt < 8; ++nt)
      #pragma unroll
      for (int j = 0; j < 4; ++j) {
        size_t idx = (rowbase + mt * 16 + kc * 4 + j) * 128 + nt * 16 + l15;
        u[idx] = f2bf(au[mt][nt][j]);
        v[idx] = f2bf(av[mt][nt][j]);
      }
}

// K3: per dst-node: gather z_src, scores+leaky_relu, softmax (alpha out, f32 exact),
//     mailbox m[sk][h] = sum_d alpha*relu(u[src]+v[n])  -> m bf16 to workspace.
__global__ __launch_bounds__(256) void k_score(
    const float* __restrict__ zIG, const int* __restrict__ src,
    const float* __restrict__ td, const u16* __restrict__ uW, const u16* __restrict__ vW,
    float* __restrict__ out, u16* __restrict__ m_ws) {
  __shared__ int srcIdx[16];
  __shared__ float zs[64 * 68];
  __shared__ float tds[16 * 68];
  __shared__ float sc[16 * 17];
  __shared__ float al[16 * 17];
  __shared__ float vn[512];

  int t = threadIdx.x, n = blockIdx.x;
  if (t < 16) srcIdx[t] = src[n * 16 + t];
  {
    int r = t >> 4, cc = t & 15;
    *(float4*)&tds[r * 68 + cc * 4] = ((const float4*)(td + (size_t)n * 1024))[r * 16 + cc];
  }
  if (t < 128) ((float4*)vn)[t] = make_float4(bf2f(vW[(size_t)n * 512 + t * 4]),
                                              bf2f(vW[(size_t)n * 512 + t * 4 + 1]),
                                              bf2f(vW[(size_t)n * 512 + t * 4 + 2]),
                                              bf2f(vW[(size_t)n * 512 + t * 4 + 3]));
  __syncthreads();
  {  // stage gathered z_src rows (f32): row ds=d*4+s, 64 floats
    int ds = t >> 2, c = t & 3;
    int sn = srcIdx[ds >> 2];
    const float4* zp = (const float4*)(zIG + (size_t)sn * 256 + (ds & 3) * 64) + c * 4;
    float4* zq = (float4*)&zs[ds * 68 + c * 16];
    #pragma unroll
    for (int i = 0; i < 4; ++i) zq[i] = zp[i];
  }
  __syncthreads();
  {  // scores + leaky_relu
    int d = t >> 4, s = (t >> 2) & 3, k = t & 3;
    int ds = d * 4 + s, sk = s * 4 + k;
    const float4* za = (const float4*)&zs[ds * 68];
    const float4* ta = (const float4*)&tds[sk * 68];
    float acc = 0.f;
    #pragma unroll
    for (int z4 = 0; z4 < 16; ++z4) acc += dot4(za[z4], ta[z4]);
    sc[d * 17 + sk] = acc > 0.f ? acc : 0.01f * acc;
  }
  __syncthreads();
  {  // softmax over d; alpha out (f32)
    int d = t >> 4, sk = t & 15;
    float mx = -3.4e38f;
    #pragma unroll
    for (int dd = 0; dd < 16; ++dd) mx = fmaxf(mx, sc[dd * 17 + sk]);
    float sum = 0.f, eown = 0.f;
    #pragma unroll
    for (int dd = 0; dd < 16; ++dd) {
      float e = expf(sc[dd * 17 + sk] - mx);
      sum += e;
      if (dd == d) eown = e;
    }
    float a = eown / sum;
    al[d * 17 + sk] = a;
    out[4194304u + (unsigned)n * 256 + t] = a;  // alpha [N][16][4][4]
  }
  __syncthreads();
  {  // mailbox: m[sk][h] = sum_d alpha * relu(u[src]+v[n]); bf16 to ws
    int h = t & 127, s0 = t >> 7;
    float mac[2][4] = {{0.f,0.f,0.f,0.f},{0.f,0.f,0.f,0.f}};
    for (int d = 0; d < 16; ++d) {
      int sn = srcIdx[d];
      #pragma unroll
      for (int pi = 0; pi < 2; ++pi) {
        int s = s0 + pi * 2;
        float uval = bf2f(uW[(size_t)sn * 512 + s * 128 + h]) + vn[s * 128 + h];
        float hid = uval > 0.f ? uval : 0.f;
        #pragma unroll
        for (int k = 0; k < 4; ++k) mac[pi][k] += al[d * 17 + s * 4 + k] * hid;
      }
    }
    #pragma unroll
    for (int pi = 0; pi < 2; ++pi) {
      int s = s0 + pi * 2;
      #pragma unroll
      for (int k = 0; k < 4; ++k)
        m_ws[(size_t)n * 2048 + (s * 4 + k) * 128 + h] = f2bf(mac[pi][k]);
    }
  }
}

// K4: fused F+G. Per block: 128 rows (n,s).
//   hid = relu(m_flat[row][512] @ WW2[128][512]^T)   (E folded into WW2)
//   out = hid @ F1w2[128][128]^T   (f32)
__global__ __launch_bounds__(256) void k_fg(const u16* __restrict__ A,
                                            const float* __restrict__ WF,
                                            const float* __restrict__ WG,
                                            float* __restrict__ out) {
  __shared__ u16 Wl[128 * 72];
  __shared__ u16 hidl[128 * 136];
  int t = threadIdx.x, lane = t & 63, w = t >> 6;
  size_t rowbase = (size_t)blockIdx.x * 128 + w * 32;
  int l15 = lane & 15, kc = lane >> 4;
  f32x4 acc[2][8];
  #pragma unroll
  for (int mt = 0; mt < 2; ++mt)
    #pragma unroll
    for (int nt = 0; nt < 8; ++nt) acc[mt][nt] = (f32x4){0.f, 0.f, 0.f, 0.f};
  // F phase: K=512 in 8 chunks
  for (int c = 0; c < 8; ++c) {
    __syncthreads();
    stage_w(WF, 512, c, Wl, t);
    __syncthreads();
    #pragma unroll
    for (int ks = 0; ks < 2; ++ks) {
      short8 af[2];
      #pragma unroll
      for (int mt = 0; mt < 2; ++mt)
        af[mt] = *(const short8*)(A + (rowbase + mt * 16 + l15) * 512 + c * 64 + ks * 32 + kc * 8);
      #pragma unroll
      for (int nt = 0; nt < 8; ++nt) {
        short8 bf = *(const short8*)&Wl[(nt * 16 + l15) * 72 + ks * 32 + kc * 8];
        #pragma unroll
        for (int mt = 0; mt < 2; ++mt)
          acc[mt][nt] = __builtin_amdgcn_mfma_f32_16x16x32_bf16(af[mt], bf, acc[mt][nt], 0, 0, 0);
      }
    }
  }
  // relu -> hid tile to LDS (bf16)
  #pragma unroll
  for (int mt = 0; mt < 2; ++mt)
    #pragma unroll
    for (int nt = 0; nt < 8; ++nt)
      #pragma unroll
      for (int j = 0; j < 4; ++j)
        hidl[(w * 32 + mt * 16 + kc * 4 + j) * 136 + nt * 16 + l15] =
            f2bf(fmaxf(acc[mt][nt][j], 0.f));
  // G phase: K=128 in 2 chunks
  f32x4 acc2[2][8];
  #pragma unroll
  for (int mt = 0; mt < 2; ++mt)
    #pragma unroll
    for (int nt = 0; nt < 8; ++nt) acc2[mt][nt] = (f32x4){0.f, 0.f, 0.f, 0.f};
  for (int c = 0; c < 2; ++c) {
    __syncthreads();   // hidl writes done (c=0) / prior reads done (c=1); Wl re-stage safe
    stage_w(WG, 128, c, Wl, t);
    __syncthreads();
    #pragma unroll
    for (int ks = 0; ks < 2; ++ks) {
      short8 af[2];
      #pragma unroll
      for (int mt = 0; mt < 2; ++mt)
        af[mt] = *(const short8*)&hidl[(w * 32 + mt * 16 + l15) * 136 + c * 64 + ks * 32 + kc * 8];
      #pragma unroll
      for (int nt = 0; nt < 8; ++nt) {
        short8 bf = *(const short8*)&Wl[(nt * 16 + l15) * 72 + ks * 32 + kc * 8];
        #pragma unroll
        for (int mt = 0; mt < 2; ++mt)
          acc2[mt][nt] = __builtin_amdgcn_mfma_f32_16x16x32_bf16(af[mt], bf, acc2[mt][nt], 0, 0, 0);
      }
    }
  }
  #pragma unroll
  for (int mt = 0; mt < 2; ++mt)
    #pragma unroll
    for (int nt = 0; nt < 8; ++nt)
      #pragma unroll
      for (int j = 0; j < 4; ++j)
        out[(rowbase + mt * 16 + kc * 4 + j) * 128 + nt * 16 + l15] = acc2[mt][nt][j];
}

extern "C" void kernel_launch(void* const* d_in, const int* in_sizes, int n_in,
                              void* d_out, int out_size, void* d_ws, size_t ws_size,
                              hipStream_t stream) {
  const float* zIG  = (const float*)d_in[0];
  const float* xt   = (const float*)d_in[1];
  const float* Ws   = (const float*)d_in[2];
  const float* Wd   = (const float*)d_in[3];
  const float* F2w1 = (const float*)d_in[4];
  const float* F2w2 = (const float*)d_in[5];
  const float* F1w1 = (const float*)d_in[6];
  const float* F1w2 = (const float*)d_in[7];
  const int* src    = (const int*)d_in[8];
  float* out = (float*)d_out;

  char* ws = (char*)d_ws;
  float* MT  = (float*)ws;                           // 64 KiB
  float* td  = (float*)(ws + 65536);                 // 32 MiB
  u16* u     = (u16*)(ws + 65536 + 33554432);        // 8 MiB
  u16* v     = u + 4194304;                          // 8 MiB
  float* WW2 = (float*)(ws + 50397184);              // 256 KiB (composite F1w1@F2w2/16)
  u16* m     = (u16*)(ws + 50659328);                // 32 MiB

  k_mt   <<<64,   256, 0, stream>>>(Ws, Wd, MT);
  k_td   <<<1024, 256, 0, stream>>>(zIG, MT, td);
  k_ww   <<<256,  256, 0, stream>>>(F1w1, F2w2, WW2);
  k_uv   <<<256,  256, 0, stream>>>(xt, F2w1, u, v);
  k_score<<<8192, 256, 0, stream>>>(zIG, src, td, u, v, out, m);
  k_fg   <<<256,  256, 0, stream>>>(m, WW2, F1w2, out);
}

// Round 6
// 122.509 us; speedup vs baseline: 4.7361x; 1.0063x over previous
//
#include <hip/hip_runtime.h>
#include <hip/hip_bf16.h>

// Problem constants: N=8192 S=4 Z=64 H=128 K=4 DEG=16. Float tensors are f32.
typedef unsigned short u16;
using ushort8 = __attribute__((ext_vector_type(8))) unsigned short;
using short8  = __attribute__((ext_vector_type(8))) short;
using f32x4   = __attribute__((ext_vector_type(4))) float;

__device__ __forceinline__ float bf2f(u16 v) {
  union { unsigned int u; float f; } x; x.u = ((unsigned int)v) << 16; return x.f;
}
__device__ __forceinline__ u16 f2bf(float f) {
  union { unsigned int u; float f; } x; x.f = f;
  unsigned int r = x.u + 0x7FFFu + ((x.u >> 16) & 1u);  // RNE
  return (u16)(r >> 16);
}
__device__ __forceinline__ float dot4(float4 a, float4 b) {
  return a.x * b.x + a.y * b.y + a.z * b.z + a.w * b.w;
}
// Stage a 128x64 f32 chunk (row stride `stride`, col offset c*64) into LDS bf16 [128][72].
__device__ __forceinline__ void stage_w(const float* g, int stride, int c, u16* Wl, int t) {
  int row = t >> 1, half = t & 1;
  const float4* gp = (const float4*)(g + (size_t)row * stride + c * 64 + half * 32);
  ushort8* d = (ushort8*)(Wl + row * 72 + half * 32);
  #pragma unroll
  for (int i = 0; i < 4; ++i) {
    float4 a = gp[2 * i], b = gp[2 * i + 1];
    ushort8 o;
    o[0] = f2bf(a.x); o[1] = f2bf(a.y); o[2] = f2bf(a.z); o[3] = f2bf(a.w);
    o[4] = f2bf(b.x); o[5] = f2bf(b.y); o[6] = f2bf(b.z); o[7] = f2bf(b.w);
    d[i] = o;
  }
}

// K1: MT[k][z2][z1] = sum_h Ws[k][h][z1] * Wd[k][h][z2]
__global__ __launch_bounds__(256) void k_mt(const float* __restrict__ Ws,
                                            const float* __restrict__ Wd,
                                            float* __restrict__ MT) {
  int t = blockIdx.x * 256 + threadIdx.x;
  int k = t >> 12, z2 = (t >> 6) & 63, z1 = t & 63;
  const float* wsp = Ws + k * 8192 + z1;
  const float* wdp = Wd + k * 8192 + z2;
  float acc = 0.f;
  #pragma unroll 8
  for (int h = 0; h < 128; ++h) acc += wsp[h * 64] * wdp[h * 64];
  MT[k * 4096 + z2 * 64 + z1] = acc;
}

// K2a: td[n][s*4+k][z1] = sum_z2 MT[k][z2][z1] * zIG[n][s][z2]; 8 nodes/block
__global__ __launch_bounds__(256) void k_td(const float* __restrict__ zIG,
                                            const float* __restrict__ MT,
                                            float* __restrict__ td) {
  __shared__ float zf[8 * 256];
  int t = threadIdx.x;
  int nb0 = blockIdx.x * 8;
  {
    const float4* zsrc = (const float4*)(zIG + (size_t)nb0 * 256);
    float4* zd = (float4*)zf;
    zd[t] = zsrc[t];
    zd[t + 256] = zsrc[t + 256];
  }
  __syncthreads();
  int s = t >> 6, k = (t >> 4) & 3, z1q = t & 15;
  const float4* mt4 = (const float4*)MT;
  float4 acc[8];
  #pragma unroll
  for (int g = 0; g < 8; ++g) acc[g] = make_float4(0.f, 0.f, 0.f, 0.f);
  for (int z2 = 0; z2 < 64; ++z2) {
    float4 mv = mt4[k * 1024 + z2 * 16 + z1q];
    #pragma unroll
    for (int g = 0; g < 8; ++g) {
      float zv = zf[g * 256 + s * 64 + z2];
      acc[g].x += mv.x * zv; acc[g].y += mv.y * zv;
      acc[g].z += mv.z * zv; acc[g].w += mv.w * zv;
    }
  }
  int sk = s * 4 + k;
  #pragma unroll
  for (int g = 0; g < 8; ++g)
    *(float4*)&td[(size_t)(nb0 + g) * 1024 + sk * 64 + z1q * 4] = acc[g];
}

// Composite epilogue weight: WW2[ho][k*128+hi] = (1/16) sum_j F1w1[ho][k*128+j]*F2w2[j][hi]
__global__ __launch_bounds__(256) void k_ww(const float* __restrict__ F1w1,
                                            const float* __restrict__ F2w2,
                                            float* __restrict__ WW2) {
  int id = blockIdx.x * 256 + threadIdx.x;   // 65536 = 128 ho x 4 k x 128 hi
  int ho = id >> 9, kk = (id >> 7) & 3, hi = id & 127;
  const float* wa = F1w1 + ho * 512 + kk * 128;  // wave-uniform -> scalar loads
  const float* wb = F2w2 + hi;                    // coalesced over hi
  float acc = 0.f;
  #pragma unroll 8
  for (int j = 0; j < 128; ++j) acc += wa[j] * wb[j * 128];
  WW2[ho * 512 + kk * 128 + hi] = acc * 0.0625f;
}

// K2b: u = xt @ F2w1[:, :128]^T, v = xt @ F2w1[:, 128:]^T in ONE pass (shared A-frags).
__global__ __launch_bounds__(256) void k_uv(const float* __restrict__ xt,
                                            const float* __restrict__ W1,   // [128][256]
                                            u16* __restrict__ u, u16* __restrict__ v) {
  __shared__ u16 Wlu[128 * 72];
  __shared__ u16 Wlv[128 * 72];
  int t = threadIdx.x, lane = t & 63, w = t >> 6;
  size_t rowbase = (size_t)blockIdx.x * 128 + w * 32;
  int l15 = lane & 15, kc = lane >> 4;
  f32x4 au[2][8], av[2][8];
  #pragma unroll
  for (int mt = 0; mt < 2; ++mt)
    #pragma unroll
    for (int nt = 0; nt < 8; ++nt) {
      au[mt][nt] = (f32x4){0.f, 0.f, 0.f, 0.f};
      av[mt][nt] = (f32x4){0.f, 0.f, 0.f, 0.f};
    }
  for (int c = 0; c < 2; ++c) {
    __syncthreads();
    stage_w(W1,       256, c, Wlu, t);
    stage_w(W1 + 128, 256, c, Wlv, t);
    __syncthreads();
    #pragma unroll
    for (int ks = 0; ks < 2; ++ks) {
      short8 af[2];
      #pragma unroll
      for (int mt = 0; mt < 2; ++mt) {
        const float* ap = xt + (rowbase + mt * 16 + l15) * 128 + c * 64 + ks * 32 + kc * 8;
        float4 a0 = *(const float4*)ap, a1 = *(const float4*)(ap + 4);
        u16 tmp[8] = {f2bf(a0.x), f2bf(a0.y), f2bf(a0.z), f2bf(a0.w),
                      f2bf(a1.x), f2bf(a1.y), f2bf(a1.z), f2bf(a1.w)};
        af[mt] = *(short8*)tmp;
      }
      #pragma unroll
      for (int nt = 0; nt < 8; ++nt) {
        short8 bu = *(const short8*)&Wlu[(nt * 16 + l15) * 72 + ks * 32 + kc * 8];
        short8 bv = *(const short8*)&Wlv[(nt * 16 + l15) * 72 + ks * 32 + kc * 8];
        #pragma unroll
        for (int mt = 0; mt < 2; ++mt) {
          au[mt][nt] = __builtin_amdgcn_mfma_f32_16x16x32_bf16(af[mt], bu, au[mt][nt], 0, 0, 0);
          av[mt][nt] = __builtin_amdgcn_mfma_f32_16x16x32_bf16(af[mt], bv, av[mt][nt], 0, 0, 0);
        }
      }
    }
  }
  #pragma unroll
  for (int mt = 0; mt < 2; ++mt)
    #pragma unroll
    for (int nt = 0; nt < 8; ++nt)
      #pragma unroll
      for (int j = 0; j < 4; ++j) {
        size_t idx = (rowbase + mt * 16 + kc * 4 + j) * 128 + nt * 16 + l15;
        u[idx] = f2bf(au[mt][nt][j]);
        v[idx] = f2bf(av[mt][nt][j]);
      }
}

// K3: per dst-node: scores (z gathered direct from global) + leaky_relu, softmax
//     (alpha out f32 exact), mailbox m -> bf16 workspace. Low LDS (~9 KB) for occupancy.
__global__ __launch_bounds__(256) void k_score(
    const float* __restrict__ zIG, const int* __restrict__ src,
    const float* __restrict__ td, const u16* __restrict__ uW, const u16* __restrict__ vW,
    float* __restrict__ out, u16* __restrict__ m_ws) {
  __shared__ int srcIdx[16];
  __shared__ float tds[16 * 68];
  __shared__ float sc[16 * 17];
  __shared__ float al[16 * 17];
  __shared__ float vn[512];

  int t = threadIdx.x, n = blockIdx.x;
  if (t < 16) srcIdx[t] = src[n * 16 + t];
  {
    int r = t >> 4, cc = t & 15;
    *(float4*)&tds[r * 68 + cc * 4] = ((const float4*)(td + (size_t)n * 1024))[r * 16 + cc];
  }
  if (t < 128) ((float4*)vn)[t] = make_float4(bf2f(vW[(size_t)n * 512 + t * 4]),
                                              bf2f(vW[(size_t)n * 512 + t * 4 + 1]),
                                              bf2f(vW[(size_t)n * 512 + t * 4 + 2]),
                                              bf2f(vW[(size_t)n * 512 + t * 4 + 3]));
  __syncthreads();
  {  // scores + leaky_relu; z rows read direct from global (L1/L2), dedup'd across k-lanes
    int d = t >> 4, s = (t >> 2) & 3, k = t & 3;
    int sn = srcIdx[d];
    const float4* zp = (const float4*)(zIG + (size_t)sn * 256 + s * 64);
    const float4* ta = (const float4*)&tds[(s * 4 + k) * 68];
    float acc = 0.f;
    #pragma unroll
    for (int z4 = 0; z4 < 16; ++z4) acc += dot4(zp[z4], ta[z4]);
    sc[d * 17 + s * 4 + k] = acc > 0.f ? acc : 0.01f * acc;
  }
  __syncthreads();
  {  // softmax over d; alpha out (f32)
    int d = t >> 4, sk = t & 15;
    float mx = -3.4e38f;
    #pragma unroll
    for (int dd = 0; dd < 16; ++dd) mx = fmaxf(mx, sc[dd * 17 + sk]);
    float sum = 0.f, eown = 0.f;
    #pragma unroll
    for (int dd = 0; dd < 16; ++dd) {
      float e = __expf(sc[dd * 17 + sk] - mx);
      sum += e;
      if (dd == d) eown = e;
    }
    float a = eown / sum;
    al[d * 17 + sk] = a;
    out[4194304u + (unsigned)n * 256 + t] = a;  // alpha [N][16][4][4]
  }
  __syncthreads();
  {  // mailbox: m[sk][h] = sum_d alpha * relu(u[src]+v[n]); bf16 to ws
    int h = t & 127, s0 = t >> 7;
    float mac[2][4] = {{0.f,0.f,0.f,0.f},{0.f,0.f,0.f,0.f}};
    for (int d = 0; d < 16; ++d) {
      int sn = srcIdx[d];
      #pragma unroll
      for (int pi = 0; pi < 2; ++pi) {
        int s = s0 + pi * 2;
        float uval = bf2f(uW[(size_t)sn * 512 + s * 128 + h]) + vn[s * 128 + h];
        float hid = uval > 0.f ? uval : 0.f;
        #pragma unroll
        for (int k = 0; k < 4; ++k) mac[pi][k] += al[d * 17 + s * 4 + k] * hid;
      }
    }
    #pragma unroll
    for (int pi = 0; pi < 2; ++pi) {
      int s = s0 + pi * 2;
      #pragma unroll
      for (int k = 0; k < 4; ++k)
        m_ws[(size_t)n * 2048 + (s * 4 + k) * 128 + h] = f2bf(mac[pi][k]);
    }
  }
}

// K4: fused F+G. Per block: 128 rows (n,s).
//   hid = relu(m_flat[row][512] @ WW2[128][512]^T)   (E folded into WW2)
//   out = hid @ F1w2[128][128]^T   (f32)
__global__ __launch_bounds__(256) void k_fg(const u16* __restrict__ A,
                                            const float* __restrict__ WF,
                                            const float* __restrict__ WG,
                                            float* __restrict__ out) {
  __shared__ u16 Wl[128 * 72];
  __shared__ u16 hidl[128 * 136];
  int t = threadIdx.x, lane = t & 63, w = t >> 6;
  size_t rowbase = (size_t)blockIdx.x * 128 + w * 32;
  int l15 = lane & 15, kc = lane >> 4;
  f32x4 acc[2][8];
  #pragma unroll
  for (int mt = 0; mt < 2; ++mt)
    #pragma unroll
    for (int nt = 0; nt < 8; ++nt) acc[mt][nt] = (f32x4){0.f, 0.f, 0.f, 0.f};
  // F phase: K=512 in 8 chunks
  for (int c = 0; c < 8; ++c) {
    __syncthreads();
    stage_w(WF, 512, c, Wl, t);
    __syncthreads();
    #pragma unroll
    for (int ks = 0; ks < 2; ++ks) {
      short8 af[2];
      #pragma unroll
      for (int mt = 0; mt < 2; ++mt)
        af[mt] = *(const short8*)(A + (rowbase + mt * 16 + l15) * 512 + c * 64 + ks * 32 + kc * 8);
      #pragma unroll
      for (int nt = 0; nt < 8; ++nt) {
        short8 bf = *(const short8*)&Wl[(nt * 16 + l15) * 72 + ks * 32 + kc * 8];
        #pragma unroll
        for (int mt = 0; mt < 2; ++mt)
          acc[mt][nt] = __builtin_amdgcn_mfma_f32_16x16x32_bf16(af[mt], bf, acc[mt][nt], 0, 0, 0);
      }
    }
  }
  // relu -> hid tile to LDS (bf16)
  #pragma unroll
  for (int mt = 0; mt < 2; ++mt)
    #pragma unroll
    for (int nt = 0; nt < 8; ++nt)
      #pragma unroll
      for (int j = 0; j < 4; ++j)
        hidl[(w * 32 + mt * 16 + kc * 4 + j) * 136 + nt * 16 + l15] =
            f2bf(fmaxf(acc[mt][nt][j], 0.f));
  // G phase: K=128 in 2 chunks
  f32x4 acc2[2][8];
  #pragma unroll
  for (int mt = 0; mt < 2; ++mt)
    #pragma unroll
    for (int nt = 0; nt < 8; ++nt) acc2[mt][nt] = (f32x4){0.f, 0.f, 0.f, 0.f};
  for (int c = 0; c < 2; ++c) {
    __syncthreads();
    stage_w(WG, 128, c, Wl, t);
    __syncthreads();
    #pragma unroll
    for (int ks = 0; ks < 2; ++ks) {
      short8 af[2];
      #pragma unroll
      for (int mt = 0; mt < 2; ++mt)
        af[mt] = *(const short8*)&hidl[(w * 32 + mt * 16 + l15) * 136 + c * 64 + ks * 32 + kc * 8];
      #pragma unroll
      for (int nt = 0; nt < 8; ++nt) {
        short8 bf = *(const short8*)&Wl[(nt * 16 + l15) * 72 + ks * 32 + kc * 8];
        #pragma unroll
        for (int mt = 0; mt < 2; ++mt)
          acc2[mt][nt] = __builtin_amdgcn_mfma_f32_16x16x32_bf16(af[mt], bf, acc2[mt][nt], 0, 0, 0);
      }
    }
  }
  #pragma unroll
  for (int mt = 0; mt < 2; ++mt)
    #pragma unroll
    for (int nt = 0; nt < 8; ++nt)
      #pragma unroll
      for (int j = 0; j < 4; ++j)
        out[(rowbase + mt * 16 + kc * 4 + j) * 128 + nt * 16 + l15] = acc2[mt][nt][j];
}

extern "C" void kernel_launch(void* const* d_in, const int* in_sizes, int n_in,
                              void* d_out, int out_size, void* d_ws, size_t ws_size,
                              hipStream_t stream) {
  const float* zIG  = (const float*)d_in[0];
  const float* xt   = (const float*)d_in[1];
  const float* Ws   = (const float*)d_in[2];
  const float* Wd   = (const float*)d_in[3];
  const float* F2w1 = (const float*)d_in[4];
  const float* F2w2 = (const float*)d_in[5];
  const float* F1w1 = (const float*)d_in[6];
  const float* F1w2 = (const float*)d_in[7];
  const int* src    = (const int*)d_in[8];
  float* out = (float*)d_out;

  char* ws = (char*)d_ws;
  float* MT  = (float*)ws;                           // 64 KiB
  float* td  = (float*)(ws + 65536);                 // 32 MiB
  u16* u     = (u16*)(ws + 65536 + 33554432);        // 8 MiB
  u16* v     = u + 4194304;                          // 8 MiB
  float* WW2 = (float*)(ws + 50397184);              // 256 KiB (composite F1w1@F2w2/16)
  u16* m     = (u16*)(ws + 50659328);                // 32 MiB

  k_mt   <<<64,   256, 0, stream>>>(Ws, Wd, MT);
  k_td   <<<1024, 256, 0, stream>>>(zIG, MT, td);
  k_ww   <<<256,  256, 0, stream>>>(F1w1, F2w2, WW2);
  k_uv   <<<256,  256, 0, stream>>>(xt, F2w1, u, v);
  k_score<<<8192, 256, 0, stream>>>(zIG, src, td, u, v, out, m);
  k_fg   <<<256,  256, 0, stream>>>(m, WW2, F1w2, out);
}

// Round 7
// 117.817 us; speedup vs baseline: 4.9247x; 1.0398x over previous
//
#include <hip/hip_runtime.h>
#include <hip/hip_bf16.h>

// Problem constants: N=8192 S=4 Z=64 H=128 K=4 DEG=16. Float tensors are f32.
typedef unsigned short u16;
typedef unsigned int u32;
using ushort8 = __attribute__((ext_vector_type(8))) unsigned short;
using short8  = __attribute__((ext_vector_type(8))) short;
using f32x4   = __attribute__((ext_vector_type(4))) float;

__device__ __forceinline__ float bf2f(u16 v) {
  union { u32 u; float f; } x; x.u = ((u32)v) << 16; return x.f;
}
__device__ __forceinline__ float u2f(u32 u) {
  union { u32 u; float f; } x; x.u = u; return x.f;
}
__device__ __forceinline__ u16 f2bf(float f) {
  union { u32 u; float f; } x; x.f = f;
  u32 r = x.u + 0x7FFFu + ((x.u >> 16) & 1u);  // RNE
  return (u16)(r >> 16);
}
__device__ __forceinline__ u32 pack2bf(float lo, float hi) {
  return (u32)f2bf(lo) | ((u32)f2bf(hi) << 16);
}
__device__ __forceinline__ float dot4(float4 a, float4 b) {
  return a.x * b.x + a.y * b.y + a.z * b.z + a.w * b.w;
}
// Stage a 128x64 f32 chunk (row stride `stride`, col offset c*64) into LDS bf16 [128][72].
__device__ __forceinline__ void stage_w(const float* g, int stride, int c, u16* Wl, int t) {
  int row = t >> 1, half = t & 1;
  const float4* gp = (const float4*)(g + (size_t)row * stride + c * 64 + half * 32);
  ushort8* d = (ushort8*)(Wl + row * 72 + half * 32);
  #pragma unroll
  for (int i = 0; i < 4; ++i) {
    float4 a = gp[2 * i], b = gp[2 * i + 1];
    ushort8 o;
    o[0] = f2bf(a.x); o[1] = f2bf(a.y); o[2] = f2bf(a.z); o[3] = f2bf(a.w);
    o[4] = f2bf(b.x); o[5] = f2bf(b.y); o[6] = f2bf(b.z); o[7] = f2bf(b.w);
    d[i] = o;
  }
}

// K_prep: blocks 0..63 = MT (MT[k][z2][z1] = sum_h Ws[k][h][z1]*Wd[k][h][z2]);
//         blocks 64..319 = WW2 composite (WW2[ho][k*128+hi] = (1/16) sum_j F1w1[ho][kk*128+j]*F2w2[j][hi])
__global__ __launch_bounds__(256) void k_prep(const float* __restrict__ Ws,
                                              const float* __restrict__ Wd,
                                              const float* __restrict__ F1w1,
                                              const float* __restrict__ F2w2,
                                              float* __restrict__ MT,
                                              float* __restrict__ WW2) {
  if (blockIdx.x < 64) {
    int t = blockIdx.x * 256 + threadIdx.x;
    int k = t >> 12, z2 = (t >> 6) & 63, z1 = t & 63;
    const float* wsp = Ws + k * 8192 + z1;
    const float* wdp = Wd + k * 8192 + z2;
    float acc = 0.f;
    #pragma unroll 8
    for (int h = 0; h < 128; ++h) acc += wsp[h * 64] * wdp[h * 64];
    MT[k * 4096 + z2 * 64 + z1] = acc;
  } else {
    int id = (blockIdx.x - 64) * 256 + threadIdx.x;  // 65536 = 128 ho x 4 k x 128 hi
    int ho = id >> 9, kk = (id >> 7) & 3, hi = id & 127;
    const float* wa = F1w1 + ho * 512 + kk * 128;
    const float* wb = F2w2 + hi;
    float acc = 0.f;
    #pragma unroll 8
    for (int j = 0; j < 128; ++j) acc += wa[j] * wb[j * 128];
    WW2[ho * 512 + kk * 128 + hi] = acc * 0.0625f;
  }
}

// K_stage2: blocks 0..1023 = td (8 nodes/block); blocks 1024..1279 = uv GEMM.
__global__ __launch_bounds__(256) void k_stage2(const float* __restrict__ zIG,
                                                const float* __restrict__ MT,
                                                const float* __restrict__ xt,
                                                const float* __restrict__ W1,
                                                float* __restrict__ td,
                                                u16* __restrict__ u, u16* __restrict__ v) {
  __shared__ __align__(16) char smem[36864];
  int t = threadIdx.x;
  if (blockIdx.x < 1024) {
    float* zf = (float*)smem;                        // 8 KB
    int nb0 = blockIdx.x * 8;
    {
      const float4* zsrc = (const float4*)(zIG + (size_t)nb0 * 256);
      float4* zd = (float4*)zf;
      zd[t] = zsrc[t];
      zd[t + 256] = zsrc[t + 256];
    }
    __syncthreads();
    int s = t >> 6, k = (t >> 4) & 3, z1q = t & 15;
    const float4* mt4 = (const float4*)MT;
    float4 acc[8];
    #pragma unroll
    for (int g = 0; g < 8; ++g) acc[g] = make_float4(0.f, 0.f, 0.f, 0.f);
    for (int z2 = 0; z2 < 64; ++z2) {
      float4 mv = mt4[k * 1024 + z2 * 16 + z1q];
      #pragma unroll
      for (int g = 0; g < 8; ++g) {
        float zv = zf[g * 256 + s * 64 + z2];
        acc[g].x += mv.x * zv; acc[g].y += mv.y * zv;
        acc[g].z += mv.z * zv; acc[g].w += mv.w * zv;
      }
    }
    int sk = s * 4 + k;
    #pragma unroll
    for (int g = 0; g < 8; ++g)
      *(float4*)&td[(size_t)(nb0 + g) * 1024 + sk * 64 + z1q * 4] = acc[g];
  } else {
    u16* Wlu = (u16*)smem;               // 18432 B
    u16* Wlv = (u16*)(smem + 18432);     // 18432 B
    int lane = t & 63, w = t >> 6;
    size_t rowbase = (size_t)(blockIdx.x - 1024) * 128 + w * 32;
    int l15 = lane & 15, kc = lane >> 4;
    f32x4 au[2][8], av[2][8];
    #pragma unroll
    for (int mt = 0; mt < 2; ++mt)
      #pragma unroll
      for (int nt = 0; nt < 8; ++nt) {
        au[mt][nt] = (f32x4){0.f, 0.f, 0.f, 0.f};
        av[mt][nt] = (f32x4){0.f, 0.f, 0.f, 0.f};
      }
    for (int c = 0; c < 2; ++c) {
      __syncthreads();
      stage_w(W1,       256, c, Wlu, t);
      stage_w(W1 + 128, 256, c, Wlv, t);
      __syncthreads();
      #pragma unroll
      for (int ks = 0; ks < 2; ++ks) {
        short8 af[2];
        #pragma unroll
        for (int mt = 0; mt < 2; ++mt) {
          const float* ap = xt + (rowbase + mt * 16 + l15) * 128 + c * 64 + ks * 32 + kc * 8;
          float4 a0 = *(const float4*)ap, a1 = *(const float4*)(ap + 4);
          u16 tmp[8] = {f2bf(a0.x), f2bf(a0.y), f2bf(a0.z), f2bf(a0.w),
                        f2bf(a1.x), f2bf(a1.y), f2bf(a1.z), f2bf(a1.w)};
          af[mt] = *(short8*)tmp;
        }
        #pragma unroll
        for (int nt = 0; nt < 8; ++nt) {
          short8 bu = *(const short8*)&Wlu[(nt * 16 + l15) * 72 + ks * 32 + kc * 8];
          short8 bv = *(const short8*)&Wlv[(nt * 16 + l15) * 72 + ks * 32 + kc * 8];
          #pragma unroll
          for (int mt = 0; mt < 2; ++mt) {
            au[mt][nt] = __builtin_amdgcn_mfma_f32_16x16x32_bf16(af[mt], bu, au[mt][nt], 0, 0, 0);
            av[mt][nt] = __builtin_amdgcn_mfma_f32_16x16x32_bf16(af[mt], bv, av[mt][nt], 0, 0, 0);
          }
        }
      }
    }
    #pragma unroll
    for (int mt = 0; mt < 2; ++mt)
      #pragma unroll
      for (int nt = 0; nt < 8; ++nt)
        #pragma unroll
        for (int j = 0; j < 4; ++j) {
          size_t idx = (rowbase + mt * 16 + kc * 4 + j) * 128 + nt * 16 + l15;
          u[idx] = f2bf(au[mt][nt][j]);
          v[idx] = f2bf(av[mt][nt][j]);
        }
  }
}

// K3: per dst-node scores/softmax/mailbox.
//  B: quad-split z gather (4 float4/thread) + shfl_xor butterfly.
//  C: 1 exp/thread + LDS exchange.
//  D: packed-u32 u gather, float4 alpha reads, m -> bf16 ws.
__global__ __launch_bounds__(256) void k_score(
    const float* __restrict__ zIG, const int* __restrict__ src,
    const float* __restrict__ td, const u16* __restrict__ uW, const u16* __restrict__ vW,
    float* __restrict__ out, u16* __restrict__ m_ws) {
  __shared__ int srcIdx[16];
  __shared__ float tds[16 * 68];   // [sk][z] pad 68
  __shared__ float s17[16 * 17];   // scores [d][sk]
  __shared__ float e17[16 * 17];   // exp    [d][sk]
  __shared__ float a20[16 * 20];   // alpha  [d][s*4+k], float4-readable per (d,s)

  int t = threadIdx.x, n = blockIdx.x;
  if (t < 16) srcIdx[t] = src[n * 16 + t];
  {
    int r = t >> 4, cc = t & 15;
    *(float4*)&tds[r * 68 + cc * 4] = ((const float4*)(td + (size_t)n * 1024))[r * 16 + cc];
  }
  __syncthreads();
  {  // phase B: scores + leaky_relu. quad lane k loads interleaved quarter (i*4+k).
    int d = t >> 4, s = (t >> 2) & 3, k = t & 3;
    int sn = srcIdx[d];
    const float4* zp = (const float4*)(zIG + (size_t)sn * 256 + s * 64);
    int base = s * 4;
    float p0 = 0.f, p1 = 0.f, p2 = 0.f, p3 = 0.f;
    #pragma unroll
    for (int i = 0; i < 4; ++i) {
      float4 zv = zp[i * 4 + k];
      int o = i * 16 + k * 4;
      p0 += dot4(zv, *(const float4*)&tds[(base + 0) * 68 + o]);
      p1 += dot4(zv, *(const float4*)&tds[(base + 1) * 68 + o]);
      p2 += dot4(zv, *(const float4*)&tds[(base + 2) * 68 + o]);
      p3 += dot4(zv, *(const float4*)&tds[(base + 3) * 68 + o]);
    }
    p0 += __shfl_xor(p0, 1); p1 += __shfl_xor(p1, 1);
    p2 += __shfl_xor(p2, 1); p3 += __shfl_xor(p3, 1);
    p0 += __shfl_xor(p0, 2); p1 += __shfl_xor(p1, 2);
    p2 += __shfl_xor(p2, 2); p3 += __shfl_xor(p3, 2);
    float acc = (k == 0) ? p0 : (k == 1) ? p1 : (k == 2) ? p2 : p3;
    s17[d * 17 + base + k] = acc > 0.f ? acc : 0.01f * acc;
  }
  __syncthreads();
  float e_own;
  int dC = t >> 4, skC = t & 15;
  {  // phase C1: max over d, own exp
    float mx = -3.4e38f;
    #pragma unroll
    for (int dd = 0; dd < 16; ++dd) mx = fmaxf(mx, s17[dd * 17 + skC]);
    e_own = __expf(s17[dC * 17 + skC] - mx);
    e17[dC * 17 + skC] = e_own;
  }
  __syncthreads();
  {  // phase C2: sum, alpha out
    float sum = 0.f;
    #pragma unroll
    for (int dd = 0; dd < 16; ++dd) sum += e17[dd * 17 + skC];
    float a = e_own / sum;
    a20[dC * 20 + skC] = a;
    out[4194304u + (unsigned)n * 256 + t] = a;  // alpha [N][16][4][4]
  }
  __syncthreads();
  {  // phase D: m[sk][h] = sum_d alpha * relu(u[src]+v[n]); packed u32 path
    int hp = t & 63, s = t >> 6;
    u32 vbits = *(const u32*)(vW + (size_t)n * 512 + s * 128 + hp * 2);
    float v_lo = u2f(vbits << 16), v_hi = u2f(vbits & 0xffff0000u);
    const u32* up = (const u32*)uW;
    float m0l = 0.f, m0h = 0.f, m1l = 0.f, m1h = 0.f;
    float m2l = 0.f, m2h = 0.f, m3l = 0.f, m3h = 0.f;
    for (int d = 0; d < 16; ++d) {
      int sn = srcIdx[d];
      u32 ub = up[(size_t)sn * 256 + s * 64 + hp];
      float r_lo = fmaxf(u2f(ub << 16) + v_lo, 0.f);
      float r_hi = fmaxf(u2f(ub & 0xffff0000u) + v_hi, 0.f);
      float4 a = *(const float4*)&a20[d * 20 + s * 4];
      m0l += a.x * r_lo; m0h += a.x * r_hi;
      m1l += a.y * r_lo; m1h += a.y * r_hi;
      m2l += a.z * r_lo; m2h += a.z * r_hi;
      m3l += a.w * r_lo; m3h += a.w * r_hi;
    }
    u32* mp = (u32*)(m_ws + (size_t)n * 2048);
    mp[(s * 4 + 0) * 64 + hp] = pack2bf(m0l, m0h);
    mp[(s * 4 + 1) * 64 + hp] = pack2bf(m1l, m1h);
    mp[(s * 4 + 2) * 64 + hp] = pack2bf(m2l, m2h);
    mp[(s * 4 + 3) * 64 + hp] = pack2bf(m3l, m3h);
  }
}

// K4: fused F+G. Per block: 128 rows (n,s).
//   hid = relu(m_flat[row][512] @ WW2[128][512]^T)   (E folded into WW2)
//   out = hid @ F1w2[128][128]^T   (f32)
__global__ __launch_bounds__(256) void k_fg(const u16* __restrict__ A,
                                            const float* __restrict__ WF,
                                            const float* __restrict__ WG,
                                            float* __restrict__ out) {
  __shared__ u16 Wl[128 * 72];
  __shared__ u16 hidl[128 * 136];
  int t = threadIdx.x, lane = t & 63, w = t >> 6;
  size_t rowbase = (size_t)blockIdx.x * 128 + w * 32;
  int l15 = lane & 15, kc = lane >> 4;
  f32x4 acc[2][8];
  #pragma unroll
  for (int mt = 0; mt < 2; ++mt)
    #pragma unroll
    for (int nt = 0; nt < 8; ++nt) acc[mt][nt] = (f32x4){0.f, 0.f, 0.f, 0.f};
  for (int c = 0; c < 8; ++c) {
    __syncthreads();
    stage_w(WF, 512, c, Wl, t);
    __syncthreads();
    #pragma unroll
    for (int ks = 0; ks < 2; ++ks) {
      short8 af[2];
      #pragma unroll
      for (int mt = 0; mt < 2; ++mt)
        af[mt] = *(const short8*)(A + (rowbase + mt * 16 + l15) * 512 + c * 64 + ks * 32 + kc * 8);
      #pragma unroll
      for (int nt = 0; nt < 8; ++nt) {
        short8 bf = *(const short8*)&Wl[(nt * 16 + l15) * 72 + ks * 32 + kc * 8];
        #pragma unroll
        for (int mt = 0; mt < 2; ++mt)
          acc[mt][nt] = __builtin_amdgcn_mfma_f32_16x16x32_bf16(af[mt], bf, acc[mt][nt], 0, 0, 0);
      }
    }
  }
  #pragma unroll
  for (int mt = 0; mt < 2; ++mt)
    #pragma unroll
    for (int nt = 0; nt < 8; ++nt)
      #pragma unroll
      for (int j = 0; j < 4; ++j)
        hidl[(w * 32 + mt * 16 + kc * 4 + j) * 136 + nt * 16 + l15] =
            f2bf(fmaxf(acc[mt][nt][j], 0.f));
  f32x4 acc2[2][8];
  #pragma unroll
  for (int mt = 0; mt < 2; ++mt)
    #pragma unroll
    for (int nt = 0; nt < 8; ++nt) acc2[mt][nt] = (f32x4){0.f, 0.f, 0.f, 0.f};
  for (int c = 0; c < 2; ++c) {
    __syncthreads();
    stage_w(WG, 128, c, Wl, t);
    __syncthreads();
    #pragma unroll
    for (int ks = 0; ks < 2; ++ks) {
      short8 af[2];
      #pragma unroll
      for (int mt = 0; mt < 2; ++mt)
        af[mt] = *(const short8*)&hidl[(w * 32 + mt * 16 + l15) * 136 + c * 64 + ks * 32 + kc * 8];
      #pragma unroll
      for (int nt = 0; nt < 8; ++nt) {
        short8 bf = *(const short8*)&Wl[(nt * 16 + l15) * 72 + ks * 32 + kc * 8];
        #pragma unroll
        for (int mt = 0; mt < 2; ++mt)
          acc2[mt][nt] = __builtin_amdgcn_mfma_f32_16x16x32_bf16(af[mt], bf, acc2[mt][nt], 0, 0, 0);
      }
    }
  }
  #pragma unroll
  for (int mt = 0; mt < 2; ++mt)
    #pragma unroll
    for (int nt = 0; nt < 8; ++nt)
      #pragma unroll
      for (int j = 0; j < 4; ++j)
        out[(rowbase + mt * 16 + kc * 4 + j) * 128 + nt * 16 + l15] = acc2[mt][nt][j];
}

extern "C" void kernel_launch(void* const* d_in, const int* in_sizes, int n_in,
                              void* d_out, int out_size, void* d_ws, size_t ws_size,
                              hipStream_t stream) {
  const float* zIG  = (const float*)d_in[0];
  const float* xt   = (const float*)d_in[1];
  const float* Ws   = (const float*)d_in[2];
  const float* Wd   = (const float*)d_in[3];
  const float* F2w1 = (const float*)d_in[4];
  const float* F2w2 = (const float*)d_in[5];
  const float* F1w1 = (const float*)d_in[6];
  const float* F1w2 = (const float*)d_in[7];
  const int* src    = (const int*)d_in[8];
  float* out = (float*)d_out;

  char* ws = (char*)d_ws;
  float* MT  = (float*)ws;                           // 64 KiB
  float* td  = (float*)(ws + 65536);                 // 32 MiB
  u16* u     = (u16*)(ws + 65536 + 33554432);        // 8 MiB
  u16* v     = u + 4194304;                          // 8 MiB
  float* WW2 = (float*)(ws + 50397184);              // 256 KiB (composite F1w1@F2w2/16)
  u16* m     = (u16*)(ws + 50659328);                // 32 MiB

  k_prep  <<<320,  256, 0, stream>>>(Ws, Wd, F1w1, F2w2, MT, WW2);
  k_stage2<<<1280, 256, 0, stream>>>(zIG, MT, xt, F2w1, td, u, v);
  k_score <<<8192, 256, 0, stream>>>(zIG, src, td, u, v, out, m);
  k_fg    <<<256,  256, 0, stream>>>(m, WW2, F1w2, out);
}

// Round 8
// 106.208 us; speedup vs baseline: 5.4630x; 1.1093x over previous
//
#include <hip/hip_runtime.h>
#include <hip/hip_bf16.h>

// Problem constants: N=8192 S=4 Z=64 H=128 K=4 DEG=16. Float tensors are f32.
typedef unsigned short u16;
typedef unsigned int u32;
using ushort8 = __attribute__((ext_vector_type(8))) unsigned short;
using short8  = __attribute__((ext_vector_type(8))) short;
using f32x4   = __attribute__((ext_vector_type(4))) float;

__device__ __forceinline__ float bf2f(u16 v) {
  union { u32 u; float f; } x; x.u = ((u32)v) << 16; return x.f;
}
__device__ __forceinline__ float u2f(u32 u) {
  union { u32 u; float f; } x; x.u = u; return x.f;
}
__device__ __forceinline__ u16 f2bf(float f) {
  union { u32 u; float f; } x; x.f = f;
  u32 r = x.u + 0x7FFFu + ((x.u >> 16) & 1u);  // RNE
  return (u16)(r >> 16);
}
__device__ __forceinline__ u32 pack2bf(float lo, float hi) {
  return (u32)f2bf(lo) | ((u32)f2bf(hi) << 16);
}
__device__ __forceinline__ float dot4(float4 a, float4 b) {
  return a.x * b.x + a.y * b.y + a.z * b.z + a.w * b.w;
}
// Split 8 f32 into bf16 hi (truncated) + bf16 lo (rounded residual): ~16-bit mantissa total.
__device__ __forceinline__ void split8(const float* ap, short8& hi, short8& lo) {
  float4 a0 = *(const float4*)ap, a1 = *(const float4*)(ap + 4);
  float e[8] = {a0.x, a0.y, a0.z, a0.w, a1.x, a1.y, a1.z, a1.w};
  u16 h[8], l[8];
  #pragma unroll
  for (int j = 0; j < 8; ++j) {
    u32 b = __float_as_uint(e[j]);
    h[j] = (u16)(b >> 16);
    l[j] = f2bf(e[j] - u2f(b & 0xffff0000u));
  }
  hi = *(short8*)h; lo = *(short8*)l;
}
// Stage a 128x64 f32 chunk (row stride `stride`, col offset c*64) into LDS bf16 [128][72].
__device__ __forceinline__ void stage_w(const float* g, int stride, int c, u16* Wl, int t) {
  int row = t >> 1, half = t & 1;
  const float4* gp = (const float4*)(g + (size_t)row * stride + c * 64 + half * 32);
  ushort8* d = (ushort8*)(Wl + row * 72 + half * 32);
  #pragma unroll
  for (int i = 0; i < 4; ++i) {
    float4 a = gp[2 * i], b = gp[2 * i + 1];
    ushort8 o;
    o[0] = f2bf(a.x); o[1] = f2bf(a.y); o[2] = f2bf(a.z); o[3] = f2bf(a.w);
    o[4] = f2bf(b.x); o[5] = f2bf(b.y); o[6] = f2bf(b.z); o[7] = f2bf(b.w);
    d[i] = o;
  }
}

// K_prep: blocks 0..63: B for td-GEMM, pre-split bf16: Bh/Bl[(k*64+z1)*64 + z2]
//         where B = sum_h Ws[k][h][z1]*Wd[k][h][z2].
//         blocks 64..319: WW2[ho][kk*128+hi] = (1/16) sum_j F1w1[ho][kk*128+j]*F2w2[j][hi]
__global__ __launch_bounds__(256) void k_prep(const float* __restrict__ Ws,
                                              const float* __restrict__ Wd,
                                              const float* __restrict__ F1w1,
                                              const float* __restrict__ F2w2,
                                              u16* __restrict__ Bh, u16* __restrict__ Bl,
                                              float* __restrict__ WW2) {
  if (blockIdx.x < 64) {
    int t = blockIdx.x * 256 + threadIdx.x;     // 16384 = k(4) x z1(64) x z2(64)
    int k = t >> 12, z1 = (t >> 6) & 63, z2 = t & 63;
    const float* wsp = Ws + k * 8192 + z1;      // uniform within wave -> scalar
    const float* wdp = Wd + k * 8192 + z2;      // z2 = lane -> coalesced
    float acc = 0.f;
    #pragma unroll 8
    for (int h = 0; h < 128; ++h) acc += wsp[h * 64] * wdp[h * 64];
    u32 b = __float_as_uint(acc);
    Bh[(k * 64 + z1) * 64 + z2] = (u16)(b >> 16);
    Bl[(k * 64 + z1) * 64 + z2] = f2bf(acc - u2f(b & 0xffff0000u));
  } else {
    int id = (blockIdx.x - 64) * 256 + threadIdx.x;  // 65536 = 128 ho x 4 kk x 128 hi
    int ho = id >> 9, kk = (id >> 7) & 3, hi = id & 127;
    const float* wa = F1w1 + ho * 512 + kk * 128;
    const float* wb = F2w2 + hi;
    float acc = 0.f;
    #pragma unroll 8
    for (int j = 0; j < 128; ++j) acc += wa[j] * wb[j * 128];
    WW2[ho * 512 + kk * 128 + hi] = acc * 0.0625f;
  }
}

// K_td: td[32768 x 256] = z[32768 x 64] @ B[64 x 256], f32-accurate via split-bf16
// (hi*hi + lo*hi + hi*lo). Block: 128 rows x 128 cols; grid = 256 rowblks x 2 colhalves.
__global__ __launch_bounds__(256) void k_td(const float* __restrict__ zIG,
                                            const u16* __restrict__ Bh_g,
                                            const u16* __restrict__ Bl_g,
                                            float* __restrict__ td) {
  __shared__ u16 Bh[128 * 72];   // 18 KB
  __shared__ u16 Bl[128 * 72];   // 18 KB
  int t = threadIdx.x, lane = t & 63, w = t >> 6;
  int chalf = blockIdx.x & 1;
  size_t rowbase = (size_t)(blockIdx.x >> 1) * 128 + w * 32;
  {  // stage B col-half: 128 cols x 64 z2, hi+lo
    int row = t >> 1, half = t & 1;
    const ushort8* gh = (const ushort8*)(Bh_g + (chalf * 128 + row) * 64 + half * 32);
    const ushort8* gl = (const ushort8*)(Bl_g + (chalf * 128 + row) * 64 + half * 32);
    ushort8* dh = (ushort8*)(Bh + row * 72 + half * 32);
    ushort8* dl = (ushort8*)(Bl + row * 72 + half * 32);
    #pragma unroll
    for (int i = 0; i < 4; ++i) { dh[i] = gh[i]; dl[i] = gl[i]; }
  }
  __syncthreads();
  int l15 = lane & 15, kc = lane >> 4;
  f32x4 acc[2][8];
  #pragma unroll
  for (int mt = 0; mt < 2; ++mt)
    #pragma unroll
    for (int nt = 0; nt < 8; ++nt) acc[mt][nt] = (f32x4){0.f, 0.f, 0.f, 0.f};
  #pragma unroll
  for (int ks = 0; ks < 2; ++ks) {
    short8 ah[2], al[2];
    #pragma unroll
    for (int mt = 0; mt < 2; ++mt)
      split8(zIG + (rowbase + mt * 16 + l15) * 64 + ks * 32 + kc * 8, ah[mt], al[mt]);
    #pragma unroll
    for (int nt = 0; nt < 8; ++nt) {
      int bo = (nt * 16 + l15) * 72 + ks * 32 + kc * 8;
      short8 bh = *(const short8*)&Bh[bo];
      short8 bl = *(const short8*)&Bl[bo];
      #pragma unroll
      for (int mt = 0; mt < 2; ++mt) {
        acc[mt][nt] = __builtin_amdgcn_mfma_f32_16x16x32_bf16(ah[mt], bh, acc[mt][nt], 0, 0, 0);
        acc[mt][nt] = __builtin_amdgcn_mfma_f32_16x16x32_bf16(al[mt], bh, acc[mt][nt], 0, 0, 0);
        acc[mt][nt] = __builtin_amdgcn_mfma_f32_16x16x32_bf16(ah[mt], bl, acc[mt][nt], 0, 0, 0);
      }
    }
  }
  #pragma unroll
  for (int mt = 0; mt < 2; ++mt)
    #pragma unroll
    for (int nt = 0; nt < 8; ++nt)
      #pragma unroll
      for (int j = 0; j < 4; ++j)
        td[(rowbase + mt * 16 + kc * 4 + j) * 256 + chalf * 128 + nt * 16 + l15] =
            acc[mt][nt][j];
}

// K_uv: u = xt @ F2w1[:, :128]^T, v = xt @ F2w1[:, 128:]^T in one pass (shared A-frags).
__global__ __launch_bounds__(256) void k_uv(const float* __restrict__ xt,
                                            const float* __restrict__ W1,   // [128][256]
                                            u16* __restrict__ u, u16* __restrict__ v) {
  __shared__ u16 Wlu[128 * 72];
  __shared__ u16 Wlv[128 * 72];
  int t = threadIdx.x, lane = t & 63, w = t >> 6;
  size_t rowbase = (size_t)blockIdx.x * 128 + w * 32;
  int l15 = lane & 15, kc = lane >> 4;
  f32x4 au[2][8], av[2][8];
  #pragma unroll
  for (int mt = 0; mt < 2; ++mt)
    #pragma unroll
    for (int nt = 0; nt < 8; ++nt) {
      au[mt][nt] = (f32x4){0.f, 0.f, 0.f, 0.f};
      av[mt][nt] = (f32x4){0.f, 0.f, 0.f, 0.f};
    }
  for (int c = 0; c < 2; ++c) {
    __syncthreads();
    stage_w(W1,       256, c, Wlu, t);
    stage_w(W1 + 128, 256, c, Wlv, t);
    __syncthreads();
    #pragma unroll
    for (int ks = 0; ks < 2; ++ks) {
      short8 af[2];
      #pragma unroll
      for (int mt = 0; mt < 2; ++mt) {
        const float* ap = xt + (rowbase + mt * 16 + l15) * 128 + c * 64 + ks * 32 + kc * 8;
        float4 a0 = *(const float4*)ap, a1 = *(const float4*)(ap + 4);
        u16 tmp[8] = {f2bf(a0.x), f2bf(a0.y), f2bf(a0.z), f2bf(a0.w),
                      f2bf(a1.x), f2bf(a1.y), f2bf(a1.z), f2bf(a1.w)};
        af[mt] = *(short8*)tmp;
      }
      #pragma unroll
      for (int nt = 0; nt < 8; ++nt) {
        short8 bu = *(const short8*)&Wlu[(nt * 16 + l15) * 72 + ks * 32 + kc * 8];
        short8 bv = *(const short8*)&Wlv[(nt * 16 + l15) * 72 + ks * 32 + kc * 8];
        #pragma unroll
        for (int mt = 0; mt < 2; ++mt) {
          au[mt][nt] = __builtin_amdgcn_mfma_f32_16x16x32_bf16(af[mt], bu, au[mt][nt], 0, 0, 0);
          av[mt][nt] = __builtin_amdgcn_mfma_f32_16x16x32_bf16(af[mt], bv, av[mt][nt], 0, 0, 0);
        }
      }
    }
  }
  #pragma unroll
  for (int mt = 0; mt < 2; ++mt)
    #pragma unroll
    for (int nt = 0; nt < 8; ++nt)
      #pragma unroll
      for (int j = 0; j < 4; ++j) {
        size_t idx = (rowbase + mt * 16 + kc * 4 + j) * 128 + nt * 16 + l15;
        u[idx] = f2bf(au[mt][nt][j]);
        v[idx] = f2bf(av[mt][nt][j]);
      }
}

// K3: per dst-node scores/softmax/mailbox (unchanged from R7).
__global__ __launch_bounds__(256) void k_score(
    const float* __restrict__ zIG, const int* __restrict__ src,
    const float* __restrict__ td, const u16* __restrict__ uW, const u16* __restrict__ vW,
    float* __restrict__ out, u16* __restrict__ m_ws) {
  __shared__ int srcIdx[16];
  __shared__ float tds[16 * 68];   // [sk][z] pad 68
  __shared__ float s17[16 * 17];   // scores [d][sk]
  __shared__ float e17[16 * 17];   // exp    [d][sk]
  __shared__ float a20[16 * 20];   // alpha  [d][s*4+k]

  int t = threadIdx.x, n = blockIdx.x;
  if (t < 16) srcIdx[t] = src[n * 16 + t];
  {
    int r = t >> 4, cc = t & 15;
    *(float4*)&tds[r * 68 + cc * 4] = ((const float4*)(td + (size_t)n * 1024))[r * 16 + cc];
  }
  __syncthreads();
  {  // phase B: scores + leaky_relu; quad lane k loads interleaved quarter.
    int d = t >> 4, s = (t >> 2) & 3, k = t & 3;
    int sn = srcIdx[d];
    const float4* zp = (const float4*)(zIG + (size_t)sn * 256 + s * 64);
    int base = s * 4;
    float p0 = 0.f, p1 = 0.f, p2 = 0.f, p3 = 0.f;
    #pragma unroll
    for (int i = 0; i < 4; ++i) {
      float4 zv = zp[i * 4 + k];
      int o = i * 16 + k * 4;
      p0 += dot4(zv, *(const float4*)&tds[(base + 0) * 68 + o]);
      p1 += dot4(zv, *(const float4*)&tds[(base + 1) * 68 + o]);
      p2 += dot4(zv, *(const float4*)&tds[(base + 2) * 68 + o]);
      p3 += dot4(zv, *(const float4*)&tds[(base + 3) * 68 + o]);
    }
    p0 += __shfl_xor(p0, 1); p1 += __shfl_xor(p1, 1);
    p2 += __shfl_xor(p2, 1); p3 += __shfl_xor(p3, 1);
    p0 += __shfl_xor(p0, 2); p1 += __shfl_xor(p1, 2);
    p2 += __shfl_xor(p2, 2); p3 += __shfl_xor(p3, 2);
    float acc = (k == 0) ? p0 : (k == 1) ? p1 : (k == 2) ? p2 : p3;
    s17[d * 17 + base + k] = acc > 0.f ? acc : 0.01f * acc;
  }
  __syncthreads();
  float e_own;
  int dC = t >> 4, skC = t & 15;
  {  // phase C1: max over d, own exp
    float mx = -3.4e38f;
    #pragma unroll
    for (int dd = 0; dd < 16; ++dd) mx = fmaxf(mx, s17[dd * 17 + skC]);
    e_own = __expf(s17[dC * 17 + skC] - mx);
    e17[dC * 17 + skC] = e_own;
  }
  __syncthreads();
  {  // phase C2: sum, alpha out
    float sum = 0.f;
    #pragma unroll
    for (int dd = 0; dd < 16; ++dd) sum += e17[dd * 17 + skC];
    float a = e_own / sum;
    a20[dC * 20 + skC] = a;
    out[4194304u + (unsigned)n * 256 + t] = a;  // alpha [N][16][4][4]
  }
  __syncthreads();
  {  // phase D: m[sk][h] = sum_d alpha * relu(u[src]+v[n]); packed u32 path
    int hp = t & 63, s = t >> 6;
    u32 vbits = *(const u32*)(vW + (size_t)n * 512 + s * 128 + hp * 2);
    float v_lo = u2f(vbits << 16), v_hi = u2f(vbits & 0xffff0000u);
    const u32* up = (const u32*)uW;
    float m0l = 0.f, m0h = 0.f, m1l = 0.f, m1h = 0.f;
    float m2l = 0.f, m2h = 0.f, m3l = 0.f, m3h = 0.f;
    for (int d = 0; d < 16; ++d) {
      int sn = srcIdx[d];
      u32 ub = up[(size_t)sn * 256 + s * 64 + hp];
      float r_lo = fmaxf(u2f(ub << 16) + v_lo, 0.f);
      float r_hi = fmaxf(u2f(ub & 0xffff0000u) + v_hi, 0.f);
      float4 a = *(const float4*)&a20[d * 20 + s * 4];
      m0l += a.x * r_lo; m0h += a.x * r_hi;
      m1l += a.y * r_lo; m1h += a.y * r_hi;
      m2l += a.z * r_lo; m2h += a.z * r_hi;
      m3l += a.w * r_lo; m3h += a.w * r_hi;
    }
    u32* mp = (u32*)(m_ws + (size_t)n * 2048);
    mp[(s * 4 + 0) * 64 + hp] = pack2bf(m0l, m0h);
    mp[(s * 4 + 1) * 64 + hp] = pack2bf(m1l, m1h);
    mp[(s * 4 + 2) * 64 + hp] = pack2bf(m2l, m2h);
    mp[(s * 4 + 3) * 64 + hp] = pack2bf(m3l, m3h);
  }
}

// K4: fused F+G (unchanged).
__global__ __launch_bounds__(256) void k_fg(const u16* __restrict__ A,
                                            const float* __restrict__ WF,
                                            const float* __restrict__ WG,
                                            float* __restrict__ out) {
  __shared__ u16 Wl[128 * 72];
  __shared__ u16 hidl[128 * 136];
  int t = threadIdx.x, lane = t & 63, w = t >> 6;
  size_t rowbase = (size_t)blockIdx.x * 128 + w * 32;
  int l15 = lane & 15, kc = lane >> 4;
  f32x4 acc[2][8];
  #pragma unroll
  for (int mt = 0; mt < 2; ++mt)
    #pragma unroll
    for (int nt = 0; nt < 8; ++nt) acc[mt][nt] = (f32x4){0.f, 0.f, 0.f, 0.f};
  for (int c = 0; c < 8; ++c) {
    __syncthreads();
    stage_w(WF, 512, c, Wl, t);
    __syncthreads();
    #pragma unroll
    for (int ks = 0; ks < 2; ++ks) {
      short8 af[2];
      #pragma unroll
      for (int mt = 0; mt < 2; ++mt)
        af[mt] = *(const short8*)(A + (rowbase + mt * 16 + l15) * 512 + c * 64 + ks * 32 + kc * 8);
      #pragma unroll
      for (int nt = 0; nt < 8; ++nt) {
        short8 bf = *(const short8*)&Wl[(nt * 16 + l15) * 72 + ks * 32 + kc * 8];
        #pragma unroll
        for (int mt = 0; mt < 2; ++mt)
          acc[mt][nt] = __builtin_amdgcn_mfma_f32_16x16x32_bf16(af[mt], bf, acc[mt][nt], 0, 0, 0);
      }
    }
  }
  #pragma unroll
  for (int mt = 0; mt < 2; ++mt)
    #pragma unroll
    for (int nt = 0; nt < 8; ++nt)
      #pragma unroll
      for (int j = 0; j < 4; ++j)
        hidl[(w * 32 + mt * 16 + kc * 4 + j) * 136 + nt * 16 + l15] =
            f2bf(fmaxf(acc[mt][nt][j], 0.f));
  f32x4 acc2[2][8];
  #pragma unroll
  for (int mt = 0; mt < 2; ++mt)
    #pragma unroll
    for (int nt = 0; nt < 8; ++nt) acc2[mt][nt] = (f32x4){0.f, 0.f, 0.f, 0.f};
  for (int c = 0; c < 2; ++c) {
    __syncthreads();
    stage_w(WG, 128, c, Wl, t);
    __syncthreads();
    #pragma unroll
    for (int ks = 0; ks < 2; ++ks) {
      short8 af[2];
      #pragma unroll
      for (int mt = 0; mt < 2; ++mt)
        af[mt] = *(const short8*)&hidl[(w * 32 + mt * 16 + l15) * 136 + c * 64 + ks * 32 + kc * 8];
      #pragma unroll
      for (int nt = 0; nt < 8; ++nt) {
        short8 bf = *(const short8*)&Wl[(nt * 16 + l15) * 72 + ks * 32 + kc * 8];
        #pragma unroll
        for (int mt = 0; mt < 2; ++mt)
          acc2[mt][nt] = __builtin_amdgcn_mfma_f32_16x16x32_bf16(af[mt], bf, acc2[mt][nt], 0, 0, 0);
      }
    }
  }
  #pragma unroll
  for (int mt = 0; mt < 2; ++mt)
    #pragma unroll
    for (int nt = 0; nt < 8; ++nt)
      #pragma unroll
      for (int j = 0; j < 4; ++j)
        out[(rowbase + mt * 16 + kc * 4 + j) * 128 + nt * 16 + l15] = acc2[mt][nt][j];
}

extern "C" void kernel_launch(void* const* d_in, const int* in_sizes, int n_in,
                              void* d_out, int out_size, void* d_ws, size_t ws_size,
                              hipStream_t stream) {
  const float* zIG  = (const float*)d_in[0];
  const float* xt   = (const float*)d_in[1];
  const float* Ws   = (const float*)d_in[2];
  const float* Wd   = (const float*)d_in[3];
  const float* F2w1 = (const float*)d_in[4];
  const float* F2w2 = (const float*)d_in[5];
  const float* F1w1 = (const float*)d_in[6];
  const float* F1w2 = (const float*)d_in[7];
  const int* src    = (const int*)d_in[8];
  float* out = (float*)d_out;

  char* ws = (char*)d_ws;
  u16* Bh    = (u16*)ws;                             // 32 KiB (td-GEMM B hi)
  u16* Bl    = Bh + 16384;                           // 32 KiB (td-GEMM B lo)
  float* td  = (float*)(ws + 65536);                 // 32 MiB
  u16* u     = (u16*)(ws + 65536 + 33554432);        // 8 MiB
  u16* v     = u + 4194304;                          // 8 MiB
  float* WW2 = (float*)(ws + 50397184);              // 256 KiB (composite F1w1@F2w2/16)
  u16* m     = (u16*)(ws + 50659328);                // 32 MiB

  k_prep <<<320,  256, 0, stream>>>(Ws, Wd, F1w1, F2w2, Bh, Bl, WW2);
  k_td   <<<512,  256, 0, stream>>>(zIG, Bh, Bl, td);
  k_uv   <<<256,  256, 0, stream>>>(xt, F2w1, u, v);
  k_score<<<8192, 256, 0, stream>>>(zIG, src, td, u, v, out, m);
  k_fg   <<<256,  256, 0, stream>>>(m, WW2, F1w2, out);
}

// Round 9
// 101.433 us; speedup vs baseline: 5.7202x; 1.0471x over previous
//
#include <hip/hip_runtime.h>
#include <hip/hip_bf16.h>

// Problem constants: N=8192 S=4 Z=64 H=128 K=4 DEG=16. Float tensors are f32.
typedef unsigned short u16;
typedef unsigned int u32;
using ushort8 = __attribute__((ext_vector_type(8))) unsigned short;
using short8  = __attribute__((ext_vector_type(8))) short;
using f32x4   = __attribute__((ext_vector_type(4))) float;

__device__ __forceinline__ float bf2f(u16 v) {
  union { u32 u; float f; } x; x.u = ((u32)v) << 16; return x.f;
}
__device__ __forceinline__ float u2f(u32 u) {
  union { u32 u; float f; } x; x.u = u; return x.f;
}
__device__ __forceinline__ u16 f2bf(float f) {
  union { u32 u; float f; } x; x.f = f;
  u32 r = x.u + 0x7FFFu + ((x.u >> 16) & 1u);  // RNE
  return (u16)(r >> 16);
}
__device__ __forceinline__ u32 pack2bf(float lo, float hi) {
  return (u32)f2bf(lo) | ((u32)f2bf(hi) << 16);
}
__device__ __forceinline__ float dot4(float4 a, float4 b) {
  return a.x * b.x + a.y * b.y + a.z * b.z + a.w * b.w;
}
// Split 8 f32 into bf16 hi (truncated) + bf16 lo (rounded residual): ~16-bit mantissa total.
__device__ __forceinline__ void split8(const float* ap, short8& hi, short8& lo) {
  float4 a0 = *(const float4*)ap, a1 = *(const float4*)(ap + 4);
  float e[8] = {a0.x, a0.y, a0.z, a0.w, a1.x, a1.y, a1.z, a1.w};
  u16 h[8], l[8];
  #pragma unroll
  for (int j = 0; j < 8; ++j) {
    u32 b = __float_as_uint(e[j]);
    h[j] = (u16)(b >> 16);
    l[j] = f2bf(e[j] - u2f(b & 0xffff0000u));
  }
  hi = *(short8*)h; lo = *(short8*)l;
}
// Stage a 128x64 f32 chunk into LDS bf16 [128][72], 256-thread version.
__device__ __forceinline__ void stage_w(const float* g, int stride, int c, u16* Wl, int t) {
  int row = t >> 1, half = t & 1;
  const float4* gp = (const float4*)(g + (size_t)row * stride + c * 64 + half * 32);
  ushort8* d = (ushort8*)(Wl + row * 72 + half * 32);
  #pragma unroll
  for (int i = 0; i < 4; ++i) {
    float4 a = gp[2 * i], b = gp[2 * i + 1];
    ushort8 o;
    o[0] = f2bf(a.x); o[1] = f2bf(a.y); o[2] = f2bf(a.z); o[3] = f2bf(a.w);
    o[4] = f2bf(b.x); o[5] = f2bf(b.y); o[6] = f2bf(b.z); o[7] = f2bf(b.w);
    d[i] = o;
  }
}
// Same, 512-thread version (each thread 16 cols of one row).
__device__ __forceinline__ void stage_w512(const float* g, int stride, int c, u16* Wl, int t) {
  int row = t >> 2, q = t & 3;
  const float4* gp = (const float4*)(g + (size_t)row * stride + c * 64 + q * 16);
  ushort8* d = (ushort8*)(Wl + row * 72 + q * 16);
  #pragma unroll
  for (int i = 0; i < 2; ++i) {
    float4 a = gp[2 * i], b = gp[2 * i + 1];
    ushort8 o;
    o[0] = f2bf(a.x); o[1] = f2bf(a.y); o[2] = f2bf(a.z); o[3] = f2bf(a.w);
    o[4] = f2bf(b.x); o[5] = f2bf(b.y); o[6] = f2bf(b.z); o[7] = f2bf(b.w);
    d[i] = o;
  }
}

// K_prep: blocks 0..63: B for td-GEMM, pre-split bf16 (Bh/Bl[(k*64+z1)*64+z2]);
//         blocks 64..319: WW2[ho][kk*128+hi] = (1/16) sum_j F1w1[ho][kk*128+j]*F2w2[j][hi]
__global__ __launch_bounds__(256) void k_prep(const float* __restrict__ Ws,
                                              const float* __restrict__ Wd,
                                              const float* __restrict__ F1w1,
                                              const float* __restrict__ F2w2,
                                              u16* __restrict__ Bh, u16* __restrict__ Bl,
                                              float* __restrict__ WW2) {
  if (blockIdx.x < 64) {
    int t = blockIdx.x * 256 + threadIdx.x;     // 16384 = k(4) x z1(64) x z2(64)
    int k = t >> 12, z1 = (t >> 6) & 63, z2 = t & 63;
    const float* wsp = Ws + k * 8192 + z1;
    const float* wdp = Wd + k * 8192 + z2;
    float acc = 0.f;
    #pragma unroll 8
    for (int h = 0; h < 128; ++h) acc += wsp[h * 64] * wdp[h * 64];
    u32 b = __float_as_uint(acc);
    Bh[(k * 64 + z1) * 64 + z2] = (u16)(b >> 16);
    Bl[(k * 64 + z1) * 64 + z2] = f2bf(acc - u2f(b & 0xffff0000u));
  } else {
    int id = (blockIdx.x - 64) * 256 + threadIdx.x;  // 65536 = 128 ho x 4 kk x 128 hi
    int ho = id >> 9, kk = (id >> 7) & 3, hi = id & 127;
    const float* wa = F1w1 + ho * 512 + kk * 128;
    const float* wb = F2w2 + hi;
    float acc = 0.f;
    #pragma unroll 8
    for (int j = 0; j < 128; ++j) acc += wa[j] * wb[j * 128];
    WW2[ho * 512 + kk * 128 + hi] = acc * 0.0625f;
  }
}

// K_tduv: blocks 0..511: td GEMM (f32-accurate split-bf16); blocks 512..767: uv GEMM.
__global__ __launch_bounds__(256) void k_tduv(const float* __restrict__ zIG,
                                              const u16* __restrict__ Bh_g,
                                              const u16* __restrict__ Bl_g,
                                              const float* __restrict__ xt,
                                              const float* __restrict__ W1,
                                              float* __restrict__ td,
                                              u16* __restrict__ u, u16* __restrict__ v) {
  __shared__ __align__(16) u16 WlA[128 * 72];
  __shared__ __align__(16) u16 WlB[128 * 72];
  int t = threadIdx.x, lane = t & 63, w = t >> 6;
  int l15 = lane & 15, kc = lane >> 4;
  if (blockIdx.x < 512) {
    u16* Bh = WlA;
    u16* Bl = WlB;
    int chalf = blockIdx.x & 1;
    size_t rowbase = (size_t)(blockIdx.x >> 1) * 128 + w * 32;
    {  // stage B col-half: 128 cols x 64 z2, hi+lo
      int row = t >> 1, half = t & 1;
      const ushort8* gh = (const ushort8*)(Bh_g + (chalf * 128 + row) * 64 + half * 32);
      const ushort8* gl = (const ushort8*)(Bl_g + (chalf * 128 + row) * 64 + half * 32);
      ushort8* dh = (ushort8*)(Bh + row * 72 + half * 32);
      ushort8* dl = (ushort8*)(Bl + row * 72 + half * 32);
      #pragma unroll
      for (int i = 0; i < 4; ++i) { dh[i] = gh[i]; dl[i] = gl[i]; }
    }
    __syncthreads();
    f32x4 acc[2][8];
    #pragma unroll
    for (int mt = 0; mt < 2; ++mt)
      #pragma unroll
      for (int nt = 0; nt < 8; ++nt) acc[mt][nt] = (f32x4){0.f, 0.f, 0.f, 0.f};
    #pragma unroll
    for (int ks = 0; ks < 2; ++ks) {
      short8 ah[2], al[2];
      #pragma unroll
      for (int mt = 0; mt < 2; ++mt)
        split8(zIG + (rowbase + mt * 16 + l15) * 64 + ks * 32 + kc * 8, ah[mt], al[mt]);
      #pragma unroll
      for (int nt = 0; nt < 8; ++nt) {
        int bo = (nt * 16 + l15) * 72 + ks * 32 + kc * 8;
        short8 bh = *(const short8*)&Bh[bo];
        short8 bl = *(const short8*)&Bl[bo];
        #pragma unroll
        for (int mt = 0; mt < 2; ++mt) {
          acc[mt][nt] = __builtin_amdgcn_mfma_f32_16x16x32_bf16(ah[mt], bh, acc[mt][nt], 0, 0, 0);
          acc[mt][nt] = __builtin_amdgcn_mfma_f32_16x16x32_bf16(al[mt], bh, acc[mt][nt], 0, 0, 0);
          acc[mt][nt] = __builtin_amdgcn_mfma_f32_16x16x32_bf16(ah[mt], bl, acc[mt][nt], 0, 0, 0);
        }
      }
    }
    #pragma unroll
    for (int mt = 0; mt < 2; ++mt)
      #pragma unroll
      for (int nt = 0; nt < 8; ++nt)
        #pragma unroll
        for (int j = 0; j < 4; ++j)
          td[(rowbase + mt * 16 + kc * 4 + j) * 256 + chalf * 128 + nt * 16 + l15] =
              acc[mt][nt][j];
  } else {
    u16* Wlu = WlA;
    u16* Wlv = WlB;
    size_t rowbase = (size_t)(blockIdx.x - 512) * 128 + w * 32;
    f32x4 au[2][8], av[2][8];
    #pragma unroll
    for (int mt = 0; mt < 2; ++mt)
      #pragma unroll
      for (int nt = 0; nt < 8; ++nt) {
        au[mt][nt] = (f32x4){0.f, 0.f, 0.f, 0.f};
        av[mt][nt] = (f32x4){0.f, 0.f, 0.f, 0.f};
      }
    for (int c = 0; c < 2; ++c) {
      __syncthreads();
      stage_w(W1,       256, c, Wlu, t);
      stage_w(W1 + 128, 256, c, Wlv, t);
      __syncthreads();
      #pragma unroll
      for (int ks = 0; ks < 2; ++ks) {
        short8 af[2];
        #pragma unroll
        for (int mt = 0; mt < 2; ++mt) {
          const float* ap = xt + (rowbase + mt * 16 + l15) * 128 + c * 64 + ks * 32 + kc * 8;
          float4 a0 = *(const float4*)ap, a1 = *(const float4*)(ap + 4);
          u16 tmp[8] = {f2bf(a0.x), f2bf(a0.y), f2bf(a0.z), f2bf(a0.w),
                        f2bf(a1.x), f2bf(a1.y), f2bf(a1.z), f2bf(a1.w)};
          af[mt] = *(short8*)tmp;
        }
        #pragma unroll
        for (int nt = 0; nt < 8; ++nt) {
          short8 bu = *(const short8*)&Wlu[(nt * 16 + l15) * 72 + ks * 32 + kc * 8];
          short8 bv = *(const short8*)&Wlv[(nt * 16 + l15) * 72 + ks * 32 + kc * 8];
          #pragma unroll
          for (int mt = 0; mt < 2; ++mt) {
            au[mt][nt] = __builtin_amdgcn_mfma_f32_16x16x32_bf16(af[mt], bu, au[mt][nt], 0, 0, 0);
            av[mt][nt] = __builtin_amdgcn_mfma_f32_16x16x32_bf16(af[mt], bv, av[mt][nt], 0, 0, 0);
          }
        }
      }
    }
    #pragma unroll
    for (int mt = 0; mt < 2; ++mt)
      #pragma unroll
      for (int nt = 0; nt < 8; ++nt)
        #pragma unroll
        for (int j = 0; j < 4; ++j) {
          size_t idx = (rowbase + mt * 16 + kc * 4 + j) * 128 + nt * 16 + l15;
          u[idx] = f2bf(au[mt][nt][j]);
          v[idx] = f2bf(av[mt][nt][j]);
        }
  }
}

// K3: scores/softmax/mailbox, 2 dst-nodes per block; u-gather preloaded into regs
// (issued before the softmax barriers, consumed in phase D).
__global__ __launch_bounds__(256) void k_score(
    const float* __restrict__ zIG, const int* __restrict__ src,
    const float* __restrict__ td, const u16* __restrict__ uW, const u16* __restrict__ vW,
    float* __restrict__ out, u16* __restrict__ m_ws) {
  __shared__ int srcIdx[32];
  __shared__ float tds[2][16 * 68];
  __shared__ float s17[2][16 * 17];
  __shared__ float e17[2][16 * 17];
  __shared__ float a20[2][16 * 20];

  int t = threadIdx.x, n0 = blockIdx.x * 2;
  if (t < 32) srcIdx[t] = src[n0 * 16 + t];
  #pragma unroll
  for (int i = 0; i < 2; ++i) {
    int idx = t + i * 256;                 // 512 float4s = both nodes' td
    int nd = idx >> 8, r = (idx >> 4) & 15, cc = idx & 15;
    *(float4*)&tds[nd][r * 68 + cc * 4] =
        ((const float4*)td)[(size_t)(n0 + nd) * 256 + r * 16 + cc];
  }
  __syncthreads();
  {  // phase B: scores + leaky_relu for both nodes; 8 gather-float4s in flight
    int d = t >> 4, s = (t >> 2) & 3, k = t & 3;
    int base = s * 4;
    float4 zr[2][4];
    #pragma unroll
    for (int nd = 0; nd < 2; ++nd) {
      int sn = srcIdx[nd * 16 + d];
      const float4* zp = (const float4*)(zIG + (size_t)sn * 256 + s * 64);
      #pragma unroll
      for (int i = 0; i < 4; ++i) zr[nd][i] = zp[i * 4 + k];
    }
    #pragma unroll
    for (int nd = 0; nd < 2; ++nd) {
      float p0 = 0.f, p1 = 0.f, p2 = 0.f, p3 = 0.f;
      #pragma unroll
      for (int i = 0; i < 4; ++i) {
        float4 zv = zr[nd][i];
        int o = i * 16 + k * 4;
        p0 += dot4(zv, *(const float4*)&tds[nd][(base + 0) * 68 + o]);
        p1 += dot4(zv, *(const float4*)&tds[nd][(base + 1) * 68 + o]);
        p2 += dot4(zv, *(const float4*)&tds[nd][(base + 2) * 68 + o]);
        p3 += dot4(zv, *(const float4*)&tds[nd][(base + 3) * 68 + o]);
      }
      p0 += __shfl_xor(p0, 1); p1 += __shfl_xor(p1, 1);
      p2 += __shfl_xor(p2, 1); p3 += __shfl_xor(p3, 1);
      p0 += __shfl_xor(p0, 2); p1 += __shfl_xor(p1, 2);
      p2 += __shfl_xor(p2, 2); p3 += __shfl_xor(p3, 2);
      float acc = (k == 0) ? p0 : (k == 1) ? p1 : (k == 2) ? p2 : p3;
      s17[nd][d * 17 + base + k] = acc > 0.f ? acc : 0.01f * acc;
    }
  }
  // u/v preload (phase-D mapping) — hides gather latency under softmax phases
  int hp = t & 63, sD = t >> 6;
  u32 upre[2][16], vbits[2];
  {
    const u32* up = (const u32*)uW;
    #pragma unroll
    for (int nd = 0; nd < 2; ++nd) {
      #pragma unroll
      for (int dd = 0; dd < 16; ++dd)
        upre[nd][dd] = up[(size_t)srcIdx[nd * 16 + dd] * 256 + sD * 64 + hp];
      vbits[nd] = *(const u32*)(vW + (size_t)(n0 + nd) * 512 + sD * 128 + hp * 2);
    }
  }
  __syncthreads();
  float e_own[2];
  int dC = t >> 4, skC = t & 15;
  #pragma unroll
  for (int nd = 0; nd < 2; ++nd) {  // phase C1: max over d, own exp
    float mx = -3.4e38f;
    #pragma unroll
    for (int dd = 0; dd < 16; ++dd) mx = fmaxf(mx, s17[nd][dd * 17 + skC]);
    e_own[nd] = __expf(s17[nd][dC * 17 + skC] - mx);
    e17[nd][dC * 17 + skC] = e_own[nd];
  }
  __syncthreads();
  #pragma unroll
  for (int nd = 0; nd < 2; ++nd) {  // phase C2: sum, alpha out
    float sum = 0.f;
    #pragma unroll
    for (int dd = 0; dd < 16; ++dd) sum += e17[nd][dd * 17 + skC];
    float a = e_own[nd] / sum;
    a20[nd][dC * 20 + skC] = a;
    out[4194304u + (unsigned)(n0 + nd) * 256 + t] = a;  // alpha [N][16][4][4]
  }
  __syncthreads();
  #pragma unroll
  for (int nd = 0; nd < 2; ++nd) {  // phase D: mailbox from preloaded u
    float v_lo = u2f(vbits[nd] << 16), v_hi = u2f(vbits[nd] & 0xffff0000u);
    float m0l = 0.f, m0h = 0.f, m1l = 0.f, m1h = 0.f;
    float m2l = 0.f, m2h = 0.f, m3l = 0.f, m3h = 0.f;
    #pragma unroll
    for (int dd = 0; dd < 16; ++dd) {
      u32 ub = upre[nd][dd];
      float r_lo = fmaxf(u2f(ub << 16) + v_lo, 0.f);
      float r_hi = fmaxf(u2f(ub & 0xffff0000u) + v_hi, 0.f);
      float4 a = *(const float4*)&a20[nd][dd * 20 + sD * 4];
      m0l += a.x * r_lo; m0h += a.x * r_hi;
      m1l += a.y * r_lo; m1h += a.y * r_hi;
      m2l += a.z * r_lo; m2h += a.z * r_hi;
      m3l += a.w * r_lo; m3h += a.w * r_hi;
    }
    u32* mp = (u32*)(m_ws + (size_t)(n0 + nd) * 2048);
    mp[(sD * 4 + 0) * 64 + hp] = pack2bf(m0l, m0h);
    mp[(sD * 4 + 1) * 64 + hp] = pack2bf(m1l, m1h);
    mp[(sD * 4 + 2) * 64 + hp] = pack2bf(m2l, m2h);
    mp[(sD * 4 + 3) * 64 + hp] = pack2bf(m3l, m3h);
  }
}

// K4: fused F+G, 512 threads / 8 waves (16 rows per wave) for latency hiding.
//   hid = relu(m_flat[row][512] @ WW2[128][512]^T); out = hid @ F1w2[128][128]^T
__global__ __launch_bounds__(512) void k_fg(const u16* __restrict__ A,
                                            const float* __restrict__ WF,
                                            const float* __restrict__ WG,
                                            float* __restrict__ out) {
  __shared__ u16 Wl[128 * 72];
  __shared__ u16 hidl[128 * 136];
  int t = threadIdx.x, lane = t & 63, w = t >> 6;
  size_t rowbase = (size_t)blockIdx.x * 128 + w * 16;
  int l15 = lane & 15, kc = lane >> 4;
  f32x4 acc[8];
  #pragma unroll
  for (int nt = 0; nt < 8; ++nt) acc[nt] = (f32x4){0.f, 0.f, 0.f, 0.f};
  for (int c = 0; c < 8; ++c) {
    __syncthreads();
    stage_w512(WF, 512, c, Wl, t);
    __syncthreads();
    #pragma unroll
    for (int ks = 0; ks < 2; ++ks) {
      short8 af = *(const short8*)(A + (rowbase + l15) * 512 + c * 64 + ks * 32 + kc * 8);
      #pragma unroll
      for (int nt = 0; nt < 8; ++nt) {
        short8 bf = *(const short8*)&Wl[(nt * 16 + l15) * 72 + ks * 32 + kc * 8];
        acc[nt] = __builtin_amdgcn_mfma_f32_16x16x32_bf16(af, bf, acc[nt], 0, 0, 0);
      }
    }
  }
  #pragma unroll
  for (int nt = 0; nt < 8; ++nt)
    #pragma unroll
    for (int j = 0; j < 4; ++j)
      hidl[(w * 16 + kc * 4 + j) * 136 + nt * 16 + l15] = f2bf(fmaxf(acc[nt][j], 0.f));
  f32x4 acc2[8];
  #pragma unroll
  for (int nt = 0; nt < 8; ++nt) acc2[nt] = (f32x4){0.f, 0.f, 0.f, 0.f};
  for (int c = 0; c < 2; ++c) {
    __syncthreads();
    stage_w512(WG, 128, c, Wl, t);
    __syncthreads();
    #pragma unroll
    for (int ks = 0; ks < 2; ++ks) {
      short8 af = *(const short8*)&hidl[(w * 16 + l15) * 136 + c * 64 + ks * 32 + kc * 8];
      #pragma unroll
      for (int nt = 0; nt < 8; ++nt) {
        short8 bf = *(const short8*)&Wl[(nt * 16 + l15) * 72 + ks * 32 + kc * 8];
        acc2[nt] = __builtin_amdgcn_mfma_f32_16x16x32_bf16(af, bf, acc2[nt], 0, 0, 0);
      }
    }
  }
  #pragma unroll
  for (int nt = 0; nt < 8; ++nt)
    #pragma unroll
    for (int j = 0; j < 4; ++j)
      out[(rowbase + kc * 4 + j) * 128 + nt * 16 + l15] = acc2[nt][j];
}

extern "C" void kernel_launch(void* const* d_in, const int* in_sizes, int n_in,
                              void* d_out, int out_size, void* d_ws, size_t ws_size,
                              hipStream_t stream) {
  const float* zIG  = (const float*)d_in[0];
  const float* xt   = (const float*)d_in[1];
  const float* Ws   = (const float*)d_in[2];
  const float* Wd   = (const float*)d_in[3];
  const float* F2w1 = (const float*)d_in[4];
  const float* F2w2 = (const float*)d_in[5];
  const float* F1w1 = (const float*)d_in[6];
  const float* F1w2 = (const float*)d_in[7];
  const int* src    = (const int*)d_in[8];
  float* out = (float*)d_out;

  char* ws = (char*)d_ws;
  u16* Bh    = (u16*)ws;                             // 32 KiB (td-GEMM B hi)
  u16* Bl    = Bh + 16384;                           // 32 KiB (td-GEMM B lo)
  float* td  = (float*)(ws + 65536);                 // 32 MiB
  u16* u     = (u16*)(ws + 65536 + 33554432);        // 8 MiB
  u16* v     = u + 4194304;                          // 8 MiB
  float* WW2 = (float*)(ws + 50397184);              // 256 KiB (composite F1w1@F2w2/16)
  u16* m     = (u16*)(ws + 50659328);                // 32 MiB

  k_prep <<<320,  256, 0, stream>>>(Ws, Wd, F1w1, F2w2, Bh, Bl, WW2);
  k_tduv <<<768,  256, 0, stream>>>(zIG, Bh, Bl, xt, F2w1, td, u, v);
  k_score<<<4096, 256, 0, stream>>>(zIG, src, td, u, v, out, m);
  k_fg   <<<256,  512, 0, stream>>>(m, WW2, F1w2, out);
}